// Round 7
// baseline (1048.402 us; speedup 1.0000x reference)
//
#include <hip/hip_runtime.h>
#include <math.h>

#define NB 32
#define HW 4096
#define NS 16
#define EDIM 256
#define FFND 1024
#define EPS_LN 1e-5f
#define EPS_ATTN 1e-5f
#define BPB 64            // sub-blocks per batch in bigpass
#define RPB 64            // rows per bigpass block (HW/BPB)
#define TROWS 32          // rows per barrier-tile inside bigpass

__device__ __forceinline__ float sigmoidf_(float x) { return 1.0f / (1.0f + __expf(-x)); }
__device__ __forceinline__ float gelu_(float x) {
    float x3 = x * x * x;
    return 0.5f * x * (1.0f + tanhf(0.7978845608028654f * (x + 0.044715f * x3)));
}

// W[j][c] = scale * sum_e w_q[e][j] * w_k[e][c]   (scale = 256^-0.5 = 1/16)
__global__ void k_prep(const float* __restrict__ w_q, const float* __restrict__ w_k,
                       float* __restrict__ W) {
    const int j = blockIdx.x;
    const int c = threadIdx.x;
    float acc = 0.f;
    for (int e = 0; e < EDIM; ++e)
        acc += w_q[e * EDIM + j] * w_k[e * EDIM + c];
    W[j * EDIM + c] = acc * 0.0625f;
}

// Tiled transpose: src[R][C] -> dst[C][R].  R,C multiples of 64. 64x64 tiles.
__global__ __launch_bounds__(256) void k_tr(const float* __restrict__ src,
                                            float* __restrict__ dst, int R, int C) {
    __shared__ float tile[64][65];
    const int tilesC = C >> 6;
    const int tR = (blockIdx.x / tilesC) << 6;
    const int tC = (blockIdx.x % tilesC) << 6;
    const int t = threadIdx.x;
    {
        const int r = t >> 2;
        const int c0 = (t & 3) << 4;
#pragma unroll
        for (int i = 0; i < 16; i += 4) {
            const float4 v = *reinterpret_cast<const float4*>(src + (size_t)(tR + r) * C + tC + c0 + i);
            tile[r][c0 + i] = v.x; tile[r][c0 + i + 1] = v.y;
            tile[r][c0 + i + 2] = v.z; tile[r][c0 + i + 3] = v.w;
        }
    }
    __syncthreads();
    {
        const int c = t >> 2;
        const int r0 = (t & 3) << 4;
#pragma unroll
        for (int i = 0; i < 16; ++i)
            dst[(size_t)(tC + c) * R + tR + r0 + i] = tile[r0 + i][c];
    }
}

// Iteration-0 only: qn = LN(query_row); qpk = qn @ W; gq/bq scalars.
__global__ void k_qproj(const float* __restrict__ qsrc, const float* __restrict__ g_q,
                        const float* __restrict__ b_q, const float* __restrict__ W,
                        const float* __restrict__ g_kv, const float* __restrict__ b_kv,
                        float* __restrict__ qpk, float* __restrict__ gqbq) {
    const int row = blockIdx.x;   // 0..511  (= b*16 + s)
    const int t = threadIdx.x;
    __shared__ float qn[EDIM];
    __shared__ float red[16];
    const float v = qsrc[(size_t)row * EDIM + t];
    float s = v, ss = v * v;
#pragma unroll
    for (int m = 1; m < 64; m <<= 1) { s += __shfl_xor(s, m); ss += __shfl_xor(ss, m); }
    const int wave = t >> 6, lane = t & 63;
    if (lane == 0) { red[wave] = s; red[8 + wave] = ss; }
    __syncthreads();
    const float st = red[0] + red[1] + red[2] + red[3];
    const float sst = red[8] + red[9] + red[10] + red[11];
    const float mean = st * (1.0f / EDIM);
    const float rstd = rsqrtf(sst * (1.0f / EDIM) - mean * mean + EPS_LN);
    qn[t] = (v - mean) * rstd * g_q[t] + b_q[t];
    __syncthreads();
    float acc = 0.f;
    for (int j = 0; j < EDIM; ++j)
        acc += qn[j] * W[j * EDIM + t];
    qpk[(size_t)row * EDIM + t] = acc;
    float u = acc * g_kv[t];
    float w2 = acc * b_kv[t];
#pragma unroll
    for (int m = 1; m < 64; m <<= 1) { u += __shfl_xor(u, m); w2 += __shfl_xor(w2, m); }
    __syncthreads();
    if (lane == 0) { red[wave] = u; red[8 + wave] = w2; }
    __syncthreads();
    if (t == 0) {
        const int b = row >> 4, sl = row & 15;
        gqbq[b * 32 + sl] = red[0] + red[1] + red[2] + red[3];
        gqbq[b * 32 + 16 + sl] = red[8] + red[9] + red[10] + red[11];
    }
}

// Streaming pass v5: no LDS stage (phase B re-reads L2-hot x from global).
// LDS ~19 KB -> 6+ blocks/CU. 2048 blocks of 64 rows.
template <bool LAST>
__global__ __launch_bounds__(256, 4) void k_bigpass(
    const float* __restrict__ input, const float* __restrict__ qpk,
    const float* __restrict__ gqbq, const float* __restrict__ g_kv,
    float* __restrict__ pacc, float* __restrict__ psum, float* __restrict__ attn_out) {
    const int b = blockIdx.x >> 6;        // /BPB
    const int sub = blockIdx.x & 63;      // %BPB
    const int t = threadIdx.x;
    const int w = t >> 6;
    const int lane = t & 63;
    const int rp = lane >> 4;
    const int j = lane & 15;

    __shared__ __align__(16) float G[NS][EDIM];     // 16 KB
    __shared__ __align__(16) float wrec[TROWS][20]; // 2.5 KB
    __shared__ float gqbq_s[2][NS];

#pragma unroll
    for (int i = 0; i < 4; ++i) {
        const int idx = i * 1024 + t * 4;
        const float4 qv = *reinterpret_cast<const float4*>(qpk + (size_t)b * 4096 + idx);
        const float4 gv = *reinterpret_cast<const float4*>(g_kv + (idx & 255));
        *reinterpret_cast<float4*>(&G[0][0] + idx) =
            make_float4(qv.x * gv.x, qv.y * gv.y, qv.z * gv.z, qv.w * gv.w);
    }
    if (t < 32) gqbq_s[t >> 4][t & 15] = gqbq[b * 32 + t];
    __syncthreads();

    float acc[4][4];
    float S[4], A[4];
#pragma unroll
    for (int si = 0; si < 4; ++si) {
        acc[si][0] = acc[si][1] = acc[si][2] = acc[si][3] = 0.f;
        S[si] = 0.f; A[si] = 0.f;
    }

    const int rowbase = sub * RPB;
    const int lrow = w * 8 + rp * 2;
#pragma unroll 1
    for (int tt = 0; tt < RPB / TROWS; ++tt) {
        const int grow = rowbase + tt * TROWS + lrow;
        const float* xa = input + ((size_t)b * HW + grow) * EDIM;

        // ---- phase A (2 rows per lane, 16 lanes per row) ----
        float pa[NS], pb[NS];
#pragma unroll
        for (int s = 0; s < NS; ++s) { pa[s] = 0.f; pb[s] = 0.f; }
        float s1a = 0.f, s2a = 0.f, s1b = 0.f, s2b = 0.f;
#pragma unroll
        for (int c = 0; c < 4; ++c) {
            const int off = (c * 16 + j) * 4;
            const float4 xA = *reinterpret_cast<const float4*>(xa + off);
            const float4 xB = *reinterpret_cast<const float4*>(xa + EDIM + off);
            s1a += xA.x + xA.y + xA.z + xA.w;
            s2a += xA.x * xA.x + xA.y * xA.y + xA.z * xA.z + xA.w * xA.w;
            s1b += xB.x + xB.y + xB.z + xB.w;
            s2b += xB.x * xB.x + xB.y * xB.y + xB.z * xB.z + xB.w * xB.w;
#pragma unroll
            for (int s = 0; s < NS; ++s) {
                const float4 gg = *reinterpret_cast<const float4*>(&G[s][off]);
                pa[s] += xA.x * gg.x + xA.y * gg.y + xA.z * gg.z + xA.w * gg.w;
                pb[s] += xB.x * gg.x + xB.y * gg.y + xB.z * gg.z + xB.w * gg.w;
            }
        }
#pragma unroll
        for (int m = 1; m < 16; m <<= 1) {
            s1a += __shfl_xor(s1a, m); s2a += __shfl_xor(s2a, m);
            s1b += __shfl_xor(s1b, m); s2b += __shfl_xor(s2b, m);
#pragma unroll
            for (int s = 0; s < NS; ++s) {
                pa[s] += __shfl_xor(pa[s], m);
                pb[s] += __shfl_xor(pb[s], m);
            }
        }
        const float meanA = s1a * (1.0f / EDIM);
        const float rstdA = rsqrtf(s2a * (1.0f / EDIM) - meanA * meanA + EPS_LN);
        const float meanB = s1b * (1.0f / EDIM);
        const float rstdB = rsqrtf(s2b * (1.0f / EDIM) - meanB * meanB + EPS_LN);
        float mxa = -1e30f, mxb = -1e30f;
#pragma unroll
        for (int s = 0; s < NS; ++s) {
            pa[s] = rstdA * (pa[s] - meanA * gqbq_s[0][s]) + gqbq_s[1][s];
            pb[s] = rstdB * (pb[s] - meanB * gqbq_s[0][s]) + gqbq_s[1][s];
            mxa = fmaxf(mxa, pa[s]); mxb = fmaxf(mxb, pb[s]);
        }
        float ta = 0.f, tb = 0.f;
#pragma unroll
        for (int s = 0; s < NS; ++s) {
            pa[s] = __expf(pa[s] - mxa); ta += pa[s];
            pb[s] = __expf(pb[s] - mxb); tb += pb[s];
        }
        const float ia = 1.0f / ta, ib = 1.0f / tb;
#pragma unroll
        for (int s = 0; s < NS; ++s) { pa[s] *= ia; pb[s] *= ib; }

        if (j == 0) {
#pragma unroll
            for (int sq = 0; sq < 4; ++sq)
                *reinterpret_cast<float4*>(&wrec[lrow][sq * 4]) =
                    make_float4(pa[sq * 4], pa[sq * 4 + 1], pa[sq * 4 + 2], pa[sq * 4 + 3]);
            wrec[lrow][16] = rstdA;
            wrec[lrow][17] = rstdA * meanA;
        } else if (j == 1) {
#pragma unroll
            for (int sq = 0; sq < 4; ++sq)
                *reinterpret_cast<float4*>(&wrec[lrow + 1][sq * 4]) =
                    make_float4(pb[sq * 4], pb[sq * 4 + 1], pb[sq * 4 + 2], pb[sq * 4 + 3]);
            wrec[lrow + 1][16] = rstdB;
            wrec[lrow + 1][17] = rstdB * meanB;
        }
        if (LAST) {
            if (j == 0) {
#pragma unroll
                for (int s = 0; s < NS; ++s)
                    attn_out[((size_t)(b * NS + s)) * HW + grow] = pa[s];
            } else if (j == 1) {
#pragma unroll
                for (int s = 0; s < NS; ++s)
                    attn_out[((size_t)(b * NS + s)) * HW + grow + 1] = pb[s];
            }
        }
        __syncthreads();

        // ---- phase B: wave w accumulates slots 4w..4w+3; x re-read from global ----
        {
            const float* xb = input + ((size_t)b * HW + rowbase + tt * TROWS) * EDIM + lane * 4;
            const int sbase = w * 4;
#pragma unroll 4
            for (int r = 0; r < TROWS; ++r) {
                const float4 xv = *reinterpret_cast<const float4*>(xb + (size_t)r * EDIM);
                const float4 at = *reinterpret_cast<const float4*>(&wrec[r][sbase]);
                const float rr = wrec[r][16];
                const float rm = wrec[r][17];
                float wg;
                wg = at.x * rr;
                acc[0][0] += wg * xv.x; acc[0][1] += wg * xv.y;
                acc[0][2] += wg * xv.z; acc[0][3] += wg * xv.w;
                S[0] += at.x; A[0] += at.x * rm;
                wg = at.y * rr;
                acc[1][0] += wg * xv.x; acc[1][1] += wg * xv.y;
                acc[1][2] += wg * xv.z; acc[1][3] += wg * xv.w;
                S[1] += at.y; A[1] += at.y * rm;
                wg = at.z * rr;
                acc[2][0] += wg * xv.x; acc[2][1] += wg * xv.y;
                acc[2][2] += wg * xv.z; acc[2][3] += wg * xv.w;
                S[2] += at.z; A[2] += at.z * rm;
                wg = at.w * rr;
                acc[3][0] += wg * xv.x; acc[3][1] += wg * xv.y;
                acc[3][2] += wg * xv.z; acc[3][3] += wg * xv.w;
                S[3] += at.w; A[3] += at.w * rm;
            }
        }
        __syncthreads();
    }

#pragma unroll
    for (int si = 0; si < 4; ++si) {
        *reinterpret_cast<float4*>(
            pacc + ((size_t)blockIdx.x * NS + w * 4 + si) * EDIM + lane * 4) =
            make_float4(acc[si][0], acc[si][1], acc[si][2], acc[si][3]);
    }
    if (lane == 0) {
#pragma unroll
        for (int si = 0; si < 4; ++si) {
            psum[blockIdx.x * 32 + w * 4 + si] = S[si];
            psum[blockIdx.x * 32 + 16 + w * 4 + si] = A[si];
        }
    }
}

// G1: partial reduce + ub + updates = ub @ w_v.T.  grid 256: (rt 0..127) x (ct 0..1)
__global__ __launch_bounds__(256) void k_upd(
    const float* __restrict__ pacc, const float* __restrict__ psum,
    const float* __restrict__ g_kv, const float* __restrict__ b_kv,
    const float* __restrict__ w_vT, float* __restrict__ updates) {
    const int rt = blockIdx.x >> 1;
    const int ct = blockIdx.x & 1;
    const int row0 = rt * 4;
    const int b = row0 >> 4;
    const int s0 = row0 & 15;
    const int t = threadIdx.x;
    __shared__ __align__(16) float ub[4][EDIM];
    __shared__ float sSA[4][2];

    if (t < 8) {
        const int r = t & 3;
        const int isA = t >> 2;
        float v = 0.f;
        for (int p = 0; p < BPB; ++p)
            v += psum[(b * BPB + p) * 32 + isA * 16 + s0 + r];
        sSA[r][isA] = v;
    }
    __syncthreads();
#pragma unroll
    for (int r = 0; r < 4; ++r) {
        float V = 0.f;
        for (int p = 0; p < BPB; ++p)
            V += pacc[((size_t)(b * BPB + p) * NS + s0 + r) * EDIM + t];
        const float Sv = sSA[r][0], Av = sSA[r][1];
        ub[r][t] = (g_kv[t] * (V - Av) + b_kv[t] * Sv) / (Sv + EPS_ATTN);
    }
    __syncthreads();

    const int c = ct * 128 + (t & 127);
    const int half = t >> 7;       // 2 rows per thread
    const float* u0 = ub[2 * half];
    const float* u1 = ub[2 * half + 1];
    float a0 = 0.f, a1 = 0.f;
#pragma unroll 4
    for (int j = 0; j < EDIM; j += 4) {
        const float4 x0 = *reinterpret_cast<const float4*>(u0 + j);
        const float4 x1 = *reinterpret_cast<const float4*>(u1 + j);
        const float w0 = w_vT[(size_t)j * EDIM + c];
        const float w1 = w_vT[(size_t)(j + 1) * EDIM + c];
        const float w2 = w_vT[(size_t)(j + 2) * EDIM + c];
        const float w3 = w_vT[(size_t)(j + 3) * EDIM + c];
        a0 += x0.x * w0 + x0.y * w1 + x0.z * w2 + x0.w * w3;
        a1 += x1.x * w0 + x1.y * w1 + x1.z * w2 + x1.w * w3;
    }
    updates[(size_t)(row0 + 2 * half) * EDIM + c] = a0;
    updates[(size_t)(row0 + 2 * half + 1) * EDIM + c] = a1;
}

// G2a: gi = upd @ w_ih.T + b_ih (ct 0..2), gh = qprev @ w_hh.T + b_hh (ct 3..5).
// grid 768: rt = bid/6 (4 rows), ct = bid%6 (256 cols).
__global__ __launch_bounds__(256) void k_gates(
    const float* __restrict__ updates, const float* __restrict__ qprev,
    const float* __restrict__ w_ihT, const float* __restrict__ w_hhT,
    const float* __restrict__ b_ih, const float* __restrict__ b_hh,
    float* __restrict__ gig) {
    const int rt = blockIdx.x / 6;
    const int ct = blockIdx.x % 6;
    const int row0 = rt * 4;
    const int t = threadIdx.x;
    const bool ih = ct < 3;
    const int lc = (ih ? ct : ct - 3) * 256 + t;   // 0..767
    const float* __restrict__ src = ih ? updates : qprev;
    const float* __restrict__ wT = ih ? w_ihT : w_hhT;

    __shared__ __align__(16) float in4[4][EDIM];
#pragma unroll
    for (int r = 0; r < 4; ++r)
        in4[r][t] = src[(size_t)(row0 + r) * EDIM + t];
    __syncthreads();

    float a0 = 0.f, a1 = 0.f, a2 = 0.f, a3 = 0.f;
#pragma unroll 4
    for (int j = 0; j < EDIM; j += 4) {
        const float4 x0 = *reinterpret_cast<const float4*>(&in4[0][j]);
        const float4 x1 = *reinterpret_cast<const float4*>(&in4[1][j]);
        const float4 x2 = *reinterpret_cast<const float4*>(&in4[2][j]);
        const float4 x3 = *reinterpret_cast<const float4*>(&in4[3][j]);
        const float w0 = wT[(size_t)j * 768 + lc];
        const float w1 = wT[(size_t)(j + 1) * 768 + lc];
        const float w2 = wT[(size_t)(j + 2) * 768 + lc];
        const float w3 = wT[(size_t)(j + 3) * 768 + lc];
        a0 += x0.x * w0 + x0.y * w1 + x0.z * w2 + x0.w * w3;
        a1 += x1.x * w0 + x1.y * w1 + x1.z * w2 + x1.w * w3;
        a2 += x2.x * w0 + x2.y * w1 + x2.z * w2 + x2.w * w3;
        a3 += x3.x * w0 + x3.y * w1 + x3.z * w2 + x3.w * w3;
    }
    const float bias = ih ? b_ih[lc] : b_hh[lc];
    const int gcol = ih ? lc : 768 + lc;
    gig[(size_t)(row0 + 0) * 1536 + gcol] = a0 + bias;
    gig[(size_t)(row0 + 1) * 1536 + gcol] = a1 + bias;
    gig[(size_t)(row0 + 2) * 1536 + gcol] = a2 + bias;
    gig[(size_t)(row0 + 3) * 1536 + gcol] = a3 + bias;
}

// G2b+G3 fused: recompute GRU pointwise + LN for this block's 4 rows, then
// h1 slice = gelu(ln2 @ w_f1T[:, ct*256..+255] + b_f1).
// grid 512: rt = bid>>2 (4 rows), ct = bid&3 (256 cols).
__global__ __launch_bounds__(256) void k_gruffn1(
    const float* __restrict__ gig, const float* __restrict__ qprev,
    const float* __restrict__ g_2, const float* __restrict__ b_2,
    const float* __restrict__ w_f1T, const float* __restrict__ b_f1,
    float* __restrict__ slots, float* __restrict__ h1) {
    const int rt = blockIdx.x >> 2;
    const int ct = blockIdx.x & 3;
    const int row0 = rt * 4;
    const int t = threadIdx.x;
    const int wave = t >> 6, lane = t & 63;
    __shared__ __align__(16) float ln2[4][EDIM];
    __shared__ float red[4][8];

    float sl[4];
#pragma unroll
    for (int r = 0; r < 4; ++r) {
        const size_t base = (size_t)(row0 + r) * 1536;
        const float ir = gig[base + t];
        const float iz = gig[base + 256 + t];
        const float inn = gig[base + 512 + t];
        const float hr = gig[base + 768 + t];
        const float hz = gig[base + 1024 + t];
        const float hn = gig[base + 1280 + t];
        const float h = qprev[(size_t)(row0 + r) * EDIM + t];
        const float rg = sigmoidf_(ir + hr);
        const float z = sigmoidf_(iz + hz);
        const float n = tanhf(inn + rg * hn);
        sl[r] = (1.0f - z) * n + z * h;
    }
    if (ct == 0) {
#pragma unroll
        for (int r = 0; r < 4; ++r)
            slots[(size_t)(row0 + r) * EDIM + t] = sl[r];
    }
    {
        float a[4], qq[4];
#pragma unroll
        for (int r = 0; r < 4; ++r) { a[r] = sl[r]; qq[r] = sl[r] * sl[r]; }
#pragma unroll
        for (int m = 1; m < 64; m <<= 1) {
#pragma unroll
            for (int r = 0; r < 4; ++r) {
                a[r] += __shfl_xor(a[r], m);
                qq[r] += __shfl_xor(qq[r], m);
            }
        }
        if (lane == 0) {
#pragma unroll
            for (int r = 0; r < 4; ++r) { red[wave][r] = a[r]; red[wave][4 + r] = qq[r]; }
        }
    }
    __syncthreads();
    {
        const float g = g_2[t], bb = b_2[t];
#pragma unroll
        for (int r = 0; r < 4; ++r) {
            const float Sv = red[0][r] + red[1][r] + red[2][r] + red[3][r];
            const float Qv = red[0][4 + r] + red[1][4 + r] + red[2][4 + r] + red[3][4 + r];
            const float mn = Sv * (1.0f / EDIM);
            const float rs = rsqrtf(Qv * (1.0f / EDIM) - mn * mn + EPS_LN);
            ln2[r][t] = (sl[r] - mn) * rs * g + bb;
        }
    }
    __syncthreads();

    const int c = ct * 256 + t;
    float a0 = 0.f, a1 = 0.f, a2 = 0.f, a3 = 0.f;
#pragma unroll 4
    for (int j = 0; j < EDIM; j += 4) {
        const float4 x0 = *reinterpret_cast<const float4*>(&ln2[0][j]);
        const float4 x1 = *reinterpret_cast<const float4*>(&ln2[1][j]);
        const float4 x2 = *reinterpret_cast<const float4*>(&ln2[2][j]);
        const float4 x3 = *reinterpret_cast<const float4*>(&ln2[3][j]);
        const float w0 = w_f1T[(size_t)j * FFND + c];
        const float w1 = w_f1T[(size_t)(j + 1) * FFND + c];
        const float w2 = w_f1T[(size_t)(j + 2) * FFND + c];
        const float w3 = w_f1T[(size_t)(j + 3) * FFND + c];
        a0 += x0.x * w0 + x0.y * w1 + x0.z * w2 + x0.w * w3;
        a1 += x1.x * w0 + x1.y * w1 + x1.z * w2 + x1.w * w3;
        a2 += x2.x * w0 + x2.y * w1 + x2.z * w2 + x2.w * w3;
        a3 += x3.x * w0 + x3.y * w1 + x3.z * w2 + x3.w * w3;
    }
    const float bf = b_f1[c];
    h1[(size_t)(row0 + 0) * FFND + c] = gelu_(a0 + bf);
    h1[(size_t)(row0 + 1) * FFND + c] = gelu_(a1 + bf);
    h1[(size_t)(row0 + 2) * FFND + c] = gelu_(a2 + bf);
    h1[(size_t)(row0 + 3) * FFND + c] = gelu_(a3 + bf);
}

// G4+G5 fused: q = slots + h1 @ w_f2.T + b_f2 (+adjust), then (if do_qpk)
// LN(q) @ W and gq/bq scalars.  grid 256 blocks x 2 rows.
__global__ __launch_bounds__(256) void k_ffn2qpk(
    const float* __restrict__ h1, const float* __restrict__ slots,
    const float* __restrict__ w_f2T, const float* __restrict__ b_f2,
    const float* __restrict__ query,
    const float* __restrict__ g_q, const float* __restrict__ b_q,
    const float* __restrict__ W,
    const float* __restrict__ g_kv, const float* __restrict__ b_kv,
    float* __restrict__ q_out, float* __restrict__ qpk, float* __restrict__ gqbq,
    int adjust, int do_qpk) {
    const int row0 = blockIdx.x * 2;
    const int t = threadIdx.x;
    const int wave = t >> 6, lane = t & 63;
    __shared__ __align__(16) float in2[2][FFND];
    __shared__ float red[4][4];
    __shared__ __align__(16) float qn[2][EDIM];

#pragma unroll
    for (int r = 0; r < 2; ++r)
        *reinterpret_cast<float4*>(&in2[r][t * 4]) =
            *reinterpret_cast<const float4*>(h1 + (size_t)(row0 + r) * FFND + t * 4);
    __syncthreads();
    float a0 = 0.f, a1 = 0.f;
#pragma unroll 4
    for (int j = 0; j < FFND; j += 4) {
        const float4 x0 = *reinterpret_cast<const float4*>(&in2[0][j]);
        const float4 x1 = *reinterpret_cast<const float4*>(&in2[1][j]);
        const float w0 = w_f2T[(size_t)j * EDIM + t];
        const float w1 = w_f2T[(size_t)(j + 1) * EDIM + t];
        const float w2 = w_f2T[(size_t)(j + 2) * EDIM + t];
        const float w3 = w_f2T[(size_t)(j + 3) * EDIM + t];
        a0 += x0.x * w0 + x0.y * w1 + x0.z * w2 + x0.w * w3;
        a1 += x1.x * w0 + x1.y * w1 + x1.z * w2 + x1.w * w3;
    }
    const float bf = b_f2[t];
    float v0 = slots[(size_t)row0 * EDIM + t] + a0 + bf;
    float v1 = slots[(size_t)(row0 + 1) * EDIM + t] + a1 + bf;
    if (adjust) {
        const float qq0 = query[(size_t)row0 * EDIM + t];
        const float qq1 = query[(size_t)(row0 + 1) * EDIM + t];
        v0 = (v0 + qq0) - qq0;
        v1 = (v1 + qq1) - qq1;
    }
    q_out[(size_t)row0 * EDIM + t] = v0;
    q_out[(size_t)(row0 + 1) * EDIM + t] = v1;

    if (!do_qpk) return;

    {
        float a0r = v0, q0 = v0 * v0, a1r = v1, q1 = v1 * v1;
#pragma unroll
        for (int m = 1; m < 64; m <<= 1) {
            a0r += __shfl_xor(a0r, m); q0 += __shfl_xor(q0, m);
            a1r += __shfl_xor(a1r, m); q1 += __shfl_xor(q1, m);
        }
        if (lane == 0) { red[wave][0] = a0r; red[wave][1] = q0; red[wave][2] = a1r; red[wave][3] = q1; }
    }
    __syncthreads();
    {
        const float S0 = red[0][0] + red[1][0] + red[2][0] + red[3][0];
        const float Q0 = red[0][1] + red[1][1] + red[2][1] + red[3][1];
        const float S1 = red[0][2] + red[1][2] + red[2][2] + red[3][2];
        const float Q1 = red[0][3] + red[1][3] + red[2][3] + red[3][3];
        const float m0 = S0 * (1.0f / EDIM);
        const float r0 = rsqrtf(Q0 * (1.0f / EDIM) - m0 * m0 + EPS_LN);
        const float m1 = S1 * (1.0f / EDIM);
        const float r1 = rsqrtf(Q1 * (1.0f / EDIM) - m1 * m1 + EPS_LN);
        const float g = g_q[t], bb = b_q[t];
        qn[0][t] = (v0 - m0) * r0 * g + bb;
        qn[1][t] = (v1 - m1) * r1 * g + bb;
    }
    __syncthreads();
    float p0 = 0.f, p1 = 0.f;
#pragma unroll 4
    for (int j = 0; j < EDIM; j += 4) {
        const float4 x0 = *reinterpret_cast<const float4*>(&qn[0][j]);
        const float4 x1 = *reinterpret_cast<const float4*>(&qn[1][j]);
        const float w0 = W[(size_t)j * EDIM + t];
        const float w1 = W[(size_t)(j + 1) * EDIM + t];
        const float w2 = W[(size_t)(j + 2) * EDIM + t];
        const float w3 = W[(size_t)(j + 3) * EDIM + t];
        p0 += x0.x * w0 + x0.y * w1 + x0.z * w2 + x0.w * w3;
        p1 += x1.x * w0 + x1.y * w1 + x1.z * w2 + x1.w * w3;
    }
    qpk[(size_t)row0 * EDIM + t] = p0;
    qpk[(size_t)(row0 + 1) * EDIM + t] = p1;
    {
        const float gk = g_kv[t], bk = b_kv[t];
        float u0 = p0 * gk, w0 = p0 * bk, u1 = p1 * gk, w1 = p1 * bk;
#pragma unroll
        for (int m = 1; m < 64; m <<= 1) {
            u0 += __shfl_xor(u0, m); w0 += __shfl_xor(w0, m);
            u1 += __shfl_xor(u1, m); w1 += __shfl_xor(w1, m);
        }
        __syncthreads();
        if (lane == 0) { red[wave][0] = u0; red[wave][1] = w0; red[wave][2] = u1; red[wave][3] = w1; }
        __syncthreads();
        if (t == 0) {
            const int b = row0 >> 4;
            const int sl = row0 & 15;
            gqbq[b * 32 + sl] = red[0][0] + red[1][0] + red[2][0] + red[3][0];
            gqbq[b * 32 + 16 + sl] = red[0][1] + red[1][1] + red[2][1] + red[3][1];
            gqbq[b * 32 + sl + 1] = red[0][2] + red[1][2] + red[2][2] + red[3][2];
            gqbq[b * 32 + 16 + sl + 1] = red[0][3] + red[1][3] + red[2][3] + red[3][3];
        }
    }
}

extern "C" void kernel_launch(void* const* d_in, const int* in_sizes, int n_in,
                              void* d_out, int out_size, void* d_ws, size_t ws_size,
                              hipStream_t stream) {
    const float* input = (const float*)d_in[0];
    const float* query = (const float*)d_in[1];
    const float* g_kv = (const float*)d_in[2];
    const float* b_kv = (const float*)d_in[3];
    const float* w_k = (const float*)d_in[4];
    const float* w_v = (const float*)d_in[5];
    const float* g_q = (const float*)d_in[6];
    const float* b_q = (const float*)d_in[7];
    const float* w_q = (const float*)d_in[8];
    const float* w_ih = (const float*)d_in[9];
    const float* w_hh = (const float*)d_in[10];
    const float* b_ih = (const float*)d_in[11];
    const float* b_hh = (const float*)d_in[12];
    const float* g_2 = (const float*)d_in[13];
    const float* b_2 = (const float*)d_in[14];
    const float* w_f1 = (const float*)d_in[15];
    const float* b_f1 = (const float*)d_in[16];
    const float* w_f2 = (const float*)d_in[17];
    const float* b_f2 = (const float*)d_in[18];

    float* ws = (float*)d_ws;
    float* W = ws;        ws += 65536;
    float* qpk = ws;      ws += 131072;
    float* gqbq = ws;     ws += 1024;
    float* psum = ws;     ws += 65536;
    float* q_ws = ws;     ws += 131072;
    float* updates = ws;  ws += 131072;
    float* slots = ws;    ws += 131072;
    float* w_vT = ws;     ws += 65536;
    float* w_ihT = ws;    ws += 196608;
    float* w_hhT = ws;    ws += 196608;
    float* w_f1T = ws;    ws += 262144;
    float* w_f2T = ws;    ws += 262144;
    float* pacc = ws;     ws += (size_t)NB * BPB * NS * EDIM;   // 32 MB
    float* gig = pacc;                        // 512*1536 overlay (after k_upd)
    float* h1 = pacc + 786432;                // 512*1024 overlay

    float* out_q = (float*)d_out;
    float* out_attn = out_q + (size_t)NB * NS * EDIM;

    k_prep<<<256, 256, 0, stream>>>(w_q, w_k, W);
    k_tr<<<16, 256, 0, stream>>>(w_v, w_vT, 256, 256);
    k_tr<<<48, 256, 0, stream>>>(w_ih, w_ihT, 768, 256);
    k_tr<<<48, 256, 0, stream>>>(w_hh, w_hhT, 768, 256);
    k_tr<<<64, 256, 0, stream>>>(w_f1, w_f1T, 1024, 256);
    k_tr<<<64, 256, 0, stream>>>(w_f2, w_f2T, 256, 1024);
    k_qproj<<<512, 256, 0, stream>>>(query, g_q, b_q, W, g_kv, b_kv, qpk, gqbq);

    const float* qprev[3] = {query, q_ws, q_ws};
    float* qdst[3] = {q_ws, q_ws, out_q};
    const int adj[3] = {0, 1, 0};

    for (int it = 0; it < 3; ++it) {
        const bool last = (it == 2);
        if (last)
            k_bigpass<true><<<NB * BPB, 256, 0, stream>>>(input, qpk, gqbq, g_kv, pacc, psum, out_attn);
        else
            k_bigpass<false><<<NB * BPB, 256, 0, stream>>>(input, qpk, gqbq, g_kv, pacc, psum, nullptr);
        k_upd<<<256, 256, 0, stream>>>(pacc, psum, g_kv, b_kv, w_vT, updates);
        k_gates<<<768, 256, 0, stream>>>(updates, qprev[it], w_ihT, w_hhT, b_ih, b_hh, gig);
        k_gruffn1<<<512, 256, 0, stream>>>(gig, qprev[it], g_2, b_2, w_f1T, b_f1, slots, h1);
        k_ffn2qpk<<<256, 256, 0, stream>>>(h1, slots, w_f2T, b_f2, query, g_q, b_q, W,
                                           g_kv, b_kv, qdst[it], qpk, gqbq,
                                           adj[it], last ? 0 : 1);
    }
}

// Round 8
// 810.936 us; speedup vs baseline: 1.2928x; 1.2928x over previous
//
#include <hip/hip_runtime.h>
#include <math.h>

#define NB 32
#define HW 4096
#define NS 16
#define EDIM 256
#define FFND 1024
#define EPS_LN 1e-5f
#define EPS_ATTN 1e-5f
#define BPB 32            // sub-blocks per batch in bigpass
#define RPB 128           // rows per bigpass block (HW/BPB)
#define TROWS 16          // rows per barrier-tile inside bigpass

__device__ __forceinline__ float sigmoidf_(float x) { return 1.0f / (1.0f + __expf(-x)); }
__device__ __forceinline__ float gelu_(float x) {
    float x3 = x * x * x;
    return 0.5f * x * (1.0f + tanhf(0.7978845608028654f * (x + 0.044715f * x3)));
}

// W[j][c] = scale * sum_e w_q[e][j] * w_k[e][c]   (scale = 256^-0.5 = 1/16)
__global__ void k_prep(const float* __restrict__ w_q, const float* __restrict__ w_k,
                       float* __restrict__ W) {
    const int j = blockIdx.x;
    const int c = threadIdx.x;
    float acc = 0.f;
    for (int e = 0; e < EDIM; ++e)
        acc += w_q[e * EDIM + j] * w_k[e * EDIM + c];
    W[j * EDIM + c] = acc * 0.0625f;
}

// Tiled transpose: src[R][C] -> dst[C][R].  R,C multiples of 64. 64x64 tiles.
__global__ __launch_bounds__(256) void k_tr(const float* __restrict__ src,
                                            float* __restrict__ dst, int R, int C) {
    __shared__ float tile[64][65];
    const int tilesC = C >> 6;
    const int tR = (blockIdx.x / tilesC) << 6;
    const int tC = (blockIdx.x % tilesC) << 6;
    const int t = threadIdx.x;
    {
        const int r = t >> 2;
        const int c0 = (t & 3) << 4;
#pragma unroll
        for (int i = 0; i < 16; i += 4) {
            const float4 v = *reinterpret_cast<const float4*>(src + (size_t)(tR + r) * C + tC + c0 + i);
            tile[r][c0 + i] = v.x; tile[r][c0 + i + 1] = v.y;
            tile[r][c0 + i + 2] = v.z; tile[r][c0 + i + 3] = v.w;
        }
    }
    __syncthreads();
    {
        const int c = t >> 2;
        const int r0 = (t & 3) << 4;
#pragma unroll
        for (int i = 0; i < 16; ++i)
            dst[(size_t)(tC + c) * R + tR + r0 + i] = tile[r0 + i][c];
    }
}

// Iteration-0 only: qn = LN(query_row); qpk = qn @ W; gq/bq scalars.
__global__ void k_qproj(const float* __restrict__ qsrc, const float* __restrict__ g_q,
                        const float* __restrict__ b_q, const float* __restrict__ W,
                        const float* __restrict__ g_kv, const float* __restrict__ b_kv,
                        float* __restrict__ qpk, float* __restrict__ gqbq) {
    const int row = blockIdx.x;   // 0..511  (= b*16 + s)
    const int t = threadIdx.x;
    __shared__ float qn[EDIM];
    __shared__ float red[16];
    const float v = qsrc[(size_t)row * EDIM + t];
    float s = v, ss = v * v;
#pragma unroll
    for (int m = 1; m < 64; m <<= 1) { s += __shfl_xor(s, m); ss += __shfl_xor(ss, m); }
    const int wave = t >> 6, lane = t & 63;
    if (lane == 0) { red[wave] = s; red[8 + wave] = ss; }
    __syncthreads();
    const float st = red[0] + red[1] + red[2] + red[3];
    const float sst = red[8] + red[9] + red[10] + red[11];
    const float mean = st * (1.0f / EDIM);
    const float rstd = rsqrtf(sst * (1.0f / EDIM) - mean * mean + EPS_LN);
    qn[t] = (v - mean) * rstd * g_q[t] + b_q[t];
    __syncthreads();
    float acc = 0.f;
    for (int j = 0; j < EDIM; ++j)
        acc += qn[j] * W[j * EDIM + t];
    qpk[(size_t)row * EDIM + t] = acc;
    float u = acc * g_kv[t];
    float w2 = acc * b_kv[t];
#pragma unroll
    for (int m = 1; m < 64; m <<= 1) { u += __shfl_xor(u, m); w2 += __shfl_xor(w2, m); }
    __syncthreads();
    if (lane == 0) { red[wave] = u; red[8 + wave] = w2; }
    __syncthreads();
    if (t == 0) {
        const int b = row >> 4, sl = row & 15;
        gqbq[b * 32 + sl] = red[0] + red[1] + red[2] + red[3];
        gqbq[b * 32 + 16 + sl] = red[8] + red[9] + red[10] + red[11];
    }
}

// Streaming pass v6: LDS-staged 16-row tiles (single global read per row per pass),
// grid 1024 (4 blocks/CU), LDS ~34 KB.
// Phase A: 1 row per 16-lane group; stage x to LDS; dot vs G; 4-step shfl reduce;
//          softmax -> wrec.
// Phase B: slot-split waves (wave w owns slots 4w..4w+3), lane = channel quad,
//          rank-4 accumulate from staged x.
template <bool LAST>
__global__ __launch_bounds__(256, 4) void k_bigpass(
    const float* __restrict__ input, const float* __restrict__ qpk,
    const float* __restrict__ gqbq, const float* __restrict__ g_kv,
    float* __restrict__ pacc, float* __restrict__ psum, float* __restrict__ attn_out) {
    const int b = blockIdx.x >> 5;        // /BPB
    const int sub = blockIdx.x & 31;      // %BPB
    const int t = threadIdx.x;
    const int w = t >> 6;
    const int lane = t & 63;
    const int g = t >> 4;      // row in tile (0..15)
    const int j = t & 15;      // channel 16th within row

    __shared__ __align__(16) float G[NS][EDIM];        // 16 KB
    __shared__ __align__(16) float stage[TROWS][264];  // 16.5 KB padded
    __shared__ __align__(16) float wrec[TROWS][20];    // attn[16], rstd, rstd*mean
    __shared__ float gqbq_s[2][NS];

    // prologue: G = g_kv (broadcast over s) * qpk[b]
#pragma unroll
    for (int i = 0; i < 4; ++i) {
        const int idx = i * 1024 + t * 4;
        const float4 qv = *reinterpret_cast<const float4*>(qpk + (size_t)b * 4096 + idx);
        const float4 gv = *reinterpret_cast<const float4*>(g_kv + (idx & 255));
        *reinterpret_cast<float4*>(&G[0][0] + idx) =
            make_float4(qv.x * gv.x, qv.y * gv.y, qv.z * gv.z, qv.w * gv.w);
    }
    if (t < 32) gqbq_s[t >> 4][t & 15] = gqbq[b * 32 + t];
    __syncthreads();

    float acc[4][4];
    float S[4], A[4];
#pragma unroll
    for (int si = 0; si < 4; ++si) {
        acc[si][0] = acc[si][1] = acc[si][2] = acc[si][3] = 0.f;
        S[si] = 0.f; A[si] = 0.f;
    }

    const int rowbase = sub * RPB;
#pragma unroll 1
    for (int tt = 0; tt < RPB / TROWS; ++tt) {
        const int grow = rowbase + tt * TROWS + g;
        const float* xa = input + ((size_t)b * HW + grow) * EDIM;

        // ---- phase A ----
        float p[NS];
#pragma unroll
        for (int s = 0; s < NS; ++s) p[s] = 0.f;
        float s1 = 0.f, s2 = 0.f;
#pragma unroll
        for (int c = 0; c < 4; ++c) {
            const int off = (c * 16 + j) * 4;
            const float4 x = *reinterpret_cast<const float4*>(xa + off);
            *reinterpret_cast<float4*>(&stage[g][off]) = x;
            s1 += x.x + x.y + x.z + x.w;
            s2 += x.x * x.x + x.y * x.y + x.z * x.z + x.w * x.w;
#pragma unroll
            for (int s = 0; s < NS; ++s) {
                const float4 gg = *reinterpret_cast<const float4*>(&G[s][off]);
                p[s] += x.x * gg.x + x.y * gg.y + x.z * gg.z + x.w * gg.w;
            }
        }
#pragma unroll
        for (int m = 1; m < 16; m <<= 1) {
            s1 += __shfl_xor(s1, m); s2 += __shfl_xor(s2, m);
#pragma unroll
            for (int s = 0; s < NS; ++s) p[s] += __shfl_xor(p[s], m);
        }
        const float mean = s1 * (1.0f / EDIM);
        const float rstd = rsqrtf(s2 * (1.0f / EDIM) - mean * mean + EPS_LN);
        float mx = -1e30f;
#pragma unroll
        for (int s = 0; s < NS; ++s) {
            p[s] = rstd * (p[s] - mean * gqbq_s[0][s]) + gqbq_s[1][s];
            mx = fmaxf(mx, p[s]);
        }
        float tot = 0.f;
#pragma unroll
        for (int s = 0; s < NS; ++s) { p[s] = __expf(p[s] - mx); tot += p[s]; }
        const float inv = 1.0f / tot;
#pragma unroll
        for (int s = 0; s < NS; ++s) p[s] *= inv;

        if (j == 0) {
#pragma unroll
            for (int sq = 0; sq < 4; ++sq)
                *reinterpret_cast<float4*>(&wrec[g][sq * 4]) =
                    make_float4(p[sq * 4], p[sq * 4 + 1], p[sq * 4 + 2], p[sq * 4 + 3]);
            wrec[g][16] = rstd;
            wrec[g][17] = rstd * mean;
            if (LAST) {
#pragma unroll
                for (int s = 0; s < NS; ++s)
                    attn_out[((size_t)(b * NS + s)) * HW + grow] = p[s];
            }
        }
        __syncthreads();

        // ---- phase B: wave w accumulates slots 4w..4w+3 from staged x ----
        {
            const int ch = lane * 4;
            const int sbase = w * 4;
#pragma unroll
            for (int r = 0; r < TROWS; ++r) {
                const float4 xv = *reinterpret_cast<const float4*>(&stage[r][ch]);
                const float4 at = *reinterpret_cast<const float4*>(&wrec[r][sbase]);
                const float rr = wrec[r][16];
                const float rm = wrec[r][17];
                float wg;
                wg = at.x * rr;
                acc[0][0] += wg * xv.x; acc[0][1] += wg * xv.y;
                acc[0][2] += wg * xv.z; acc[0][3] += wg * xv.w;
                S[0] += at.x; A[0] += at.x * rm;
                wg = at.y * rr;
                acc[1][0] += wg * xv.x; acc[1][1] += wg * xv.y;
                acc[1][2] += wg * xv.z; acc[1][3] += wg * xv.w;
                S[1] += at.y; A[1] += at.y * rm;
                wg = at.z * rr;
                acc[2][0] += wg * xv.x; acc[2][1] += wg * xv.y;
                acc[2][2] += wg * xv.z; acc[2][3] += wg * xv.w;
                S[2] += at.z; A[2] += at.z * rm;
                wg = at.w * rr;
                acc[3][0] += wg * xv.x; acc[3][1] += wg * xv.y;
                acc[3][2] += wg * xv.z; acc[3][3] += wg * xv.w;
                S[3] += at.w; A[3] += at.w * rm;
            }
        }
        __syncthreads();
    }

    // epilogue: each wave writes its own 4 slots
#pragma unroll
    for (int si = 0; si < 4; ++si) {
        *reinterpret_cast<float4*>(
            pacc + ((size_t)blockIdx.x * NS + w * 4 + si) * EDIM + lane * 4) =
            make_float4(acc[si][0], acc[si][1], acc[si][2], acc[si][3]);
    }
    if (lane == 0) {
#pragma unroll
        for (int si = 0; si < 4; ++si) {
            psum[blockIdx.x * 32 + w * 4 + si] = S[si];
            psum[blockIdx.x * 32 + 16 + w * 4 + si] = A[si];
        }
    }
}

// G1: partial reduce + ub + updates = ub @ w_v.T.  grid 256: (rt 0..127) x (ct 0..1)
__global__ __launch_bounds__(256) void k_upd(
    const float* __restrict__ pacc, const float* __restrict__ psum,
    const float* __restrict__ g_kv, const float* __restrict__ b_kv,
    const float* __restrict__ w_vT, float* __restrict__ updates) {
    const int rt = blockIdx.x >> 1;
    const int ct = blockIdx.x & 1;
    const int row0 = rt * 4;
    const int b = row0 >> 4;
    const int s0 = row0 & 15;
    const int t = threadIdx.x;
    __shared__ __align__(16) float ub[4][EDIM];
    __shared__ float sSA[4][2];

    if (t < 8) {
        const int r = t & 3;
        const int isA = t >> 2;
        float v = 0.f;
        for (int p = 0; p < BPB; ++p)
            v += psum[(b * BPB + p) * 32 + isA * 16 + s0 + r];
        sSA[r][isA] = v;
    }
    __syncthreads();
#pragma unroll
    for (int r = 0; r < 4; ++r) {
        float V = 0.f;
        for (int p = 0; p < BPB; ++p)
            V += pacc[((size_t)(b * BPB + p) * NS + s0 + r) * EDIM + t];
        const float Sv = sSA[r][0], Av = sSA[r][1];
        ub[r][t] = (g_kv[t] * (V - Av) + b_kv[t] * Sv) / (Sv + EPS_ATTN);
    }
    __syncthreads();

    const int c = ct * 128 + (t & 127);
    const int half = t >> 7;       // 2 rows per thread
    const float* u0 = ub[2 * half];
    const float* u1 = ub[2 * half + 1];
    float a0 = 0.f, a1 = 0.f;
#pragma unroll 4
    for (int j = 0; j < EDIM; j += 4) {
        const float4 x0 = *reinterpret_cast<const float4*>(u0 + j);
        const float4 x1 = *reinterpret_cast<const float4*>(u1 + j);
        const float w0 = w_vT[(size_t)j * EDIM + c];
        const float w1 = w_vT[(size_t)(j + 1) * EDIM + c];
        const float w2 = w_vT[(size_t)(j + 2) * EDIM + c];
        const float w3 = w_vT[(size_t)(j + 3) * EDIM + c];
        a0 += x0.x * w0 + x0.y * w1 + x0.z * w2 + x0.w * w3;
        a1 += x1.x * w0 + x1.y * w1 + x1.z * w2 + x1.w * w3;
    }
    updates[(size_t)(row0 + 2 * half) * EDIM + c] = a0;
    updates[(size_t)(row0 + 2 * half + 1) * EDIM + c] = a1;
}

// G2a: gi = upd @ w_ih.T + b_ih (ct 0..2), gh = qprev @ w_hh.T + b_hh (ct 3..5).
// grid 768: rt = bid/6 (4 rows), ct = bid%6 (256 cols).
__global__ __launch_bounds__(256) void k_gates(
    const float* __restrict__ updates, const float* __restrict__ qprev,
    const float* __restrict__ w_ihT, const float* __restrict__ w_hhT,
    const float* __restrict__ b_ih, const float* __restrict__ b_hh,
    float* __restrict__ gig) {
    const int rt = blockIdx.x / 6;
    const int ct = blockIdx.x % 6;
    const int row0 = rt * 4;
    const int t = threadIdx.x;
    const bool ih = ct < 3;
    const int lc = (ih ? ct : ct - 3) * 256 + t;   // 0..767
    const float* __restrict__ src = ih ? updates : qprev;
    const float* __restrict__ wT = ih ? w_ihT : w_hhT;

    __shared__ __align__(16) float in4[4][EDIM];
#pragma unroll
    for (int r = 0; r < 4; ++r)
        in4[r][t] = src[(size_t)(row0 + r) * EDIM + t];
    __syncthreads();

    float a0 = 0.f, a1 = 0.f, a2 = 0.f, a3 = 0.f;
#pragma unroll 4
    for (int j = 0; j < EDIM; j += 4) {
        const float4 x0 = *reinterpret_cast<const float4*>(&in4[0][j]);
        const float4 x1 = *reinterpret_cast<const float4*>(&in4[1][j]);
        const float4 x2 = *reinterpret_cast<const float4*>(&in4[2][j]);
        const float4 x3 = *reinterpret_cast<const float4*>(&in4[3][j]);
        const float w0 = wT[(size_t)j * 768 + lc];
        const float w1 = wT[(size_t)(j + 1) * 768 + lc];
        const float w2 = wT[(size_t)(j + 2) * 768 + lc];
        const float w3 = wT[(size_t)(j + 3) * 768 + lc];
        a0 += x0.x * w0 + x0.y * w1 + x0.z * w2 + x0.w * w3;
        a1 += x1.x * w0 + x1.y * w1 + x1.z * w2 + x1.w * w3;
        a2 += x2.x * w0 + x2.y * w1 + x2.z * w2 + x2.w * w3;
        a3 += x3.x * w0 + x3.y * w1 + x3.z * w2 + x3.w * w3;
    }
    const float bias = ih ? b_ih[lc] : b_hh[lc];
    const int gcol = ih ? lc : 768 + lc;
    gig[(size_t)(row0 + 0) * 1536 + gcol] = a0 + bias;
    gig[(size_t)(row0 + 1) * 1536 + gcol] = a1 + bias;
    gig[(size_t)(row0 + 2) * 1536 + gcol] = a2 + bias;
    gig[(size_t)(row0 + 3) * 1536 + gcol] = a3 + bias;
}

// G2b+G3 fused: recompute GRU pointwise + LN for this block's 4 rows, then
// h1 slice = gelu(ln2 @ w_f1T[:, ct*256..+255] + b_f1).
// grid 512: rt = bid>>2 (4 rows), ct = bid&3 (256 cols).
__global__ __launch_bounds__(256) void k_gruffn1(
    const float* __restrict__ gig, const float* __restrict__ qprev,
    const float* __restrict__ g_2, const float* __restrict__ b_2,
    const float* __restrict__ w_f1T, const float* __restrict__ b_f1,
    float* __restrict__ slots, float* __restrict__ h1) {
    const int rt = blockIdx.x >> 2;
    const int ct = blockIdx.x & 3;
    const int row0 = rt * 4;
    const int t = threadIdx.x;
    const int wave = t >> 6, lane = t & 63;
    __shared__ __align__(16) float ln2[4][EDIM];
    __shared__ float red[4][8];

    float sl[4];
#pragma unroll
    for (int r = 0; r < 4; ++r) {
        const size_t base = (size_t)(row0 + r) * 1536;
        const float ir = gig[base + t];
        const float iz = gig[base + 256 + t];
        const float inn = gig[base + 512 + t];
        const float hr = gig[base + 768 + t];
        const float hz = gig[base + 1024 + t];
        const float hn = gig[base + 1280 + t];
        const float h = qprev[(size_t)(row0 + r) * EDIM + t];
        const float rg = sigmoidf_(ir + hr);
        const float z = sigmoidf_(iz + hz);
        const float n = tanhf(inn + rg * hn);
        sl[r] = (1.0f - z) * n + z * h;
    }
    if (ct == 0) {
#pragma unroll
        for (int r = 0; r < 4; ++r)
            slots[(size_t)(row0 + r) * EDIM + t] = sl[r];
    }
    {
        float a[4], qq[4];
#pragma unroll
        for (int r = 0; r < 4; ++r) { a[r] = sl[r]; qq[r] = sl[r] * sl[r]; }
#pragma unroll
        for (int m = 1; m < 64; m <<= 1) {
#pragma unroll
            for (int r = 0; r < 4; ++r) {
                a[r] += __shfl_xor(a[r], m);
                qq[r] += __shfl_xor(qq[r], m);
            }
        }
        if (lane == 0) {
#pragma unroll
            for (int r = 0; r < 4; ++r) { red[wave][r] = a[r]; red[wave][4 + r] = qq[r]; }
        }
    }
    __syncthreads();
    {
        const float g = g_2[t], bb = b_2[t];
#pragma unroll
        for (int r = 0; r < 4; ++r) {
            const float Sv = red[0][r] + red[1][r] + red[2][r] + red[3][r];
            const float Qv = red[0][4 + r] + red[1][4 + r] + red[2][4 + r] + red[3][4 + r];
            const float mn = Sv * (1.0f / EDIM);
            const float rs = rsqrtf(Qv * (1.0f / EDIM) - mn * mn + EPS_LN);
            ln2[r][t] = (sl[r] - mn) * rs * g + bb;
        }
    }
    __syncthreads();

    const int c = ct * 256 + t;
    float a0 = 0.f, a1 = 0.f, a2 = 0.f, a3 = 0.f;
#pragma unroll 4
    for (int j = 0; j < EDIM; j += 4) {
        const float4 x0 = *reinterpret_cast<const float4*>(&ln2[0][j]);
        const float4 x1 = *reinterpret_cast<const float4*>(&ln2[1][j]);
        const float4 x2 = *reinterpret_cast<const float4*>(&ln2[2][j]);
        const float4 x3 = *reinterpret_cast<const float4*>(&ln2[3][j]);
        const float w0 = w_f1T[(size_t)j * FFND + c];
        const float w1 = w_f1T[(size_t)(j + 1) * FFND + c];
        const float w2 = w_f1T[(size_t)(j + 2) * FFND + c];
        const float w3 = w_f1T[(size_t)(j + 3) * FFND + c];
        a0 += x0.x * w0 + x0.y * w1 + x0.z * w2 + x0.w * w3;
        a1 += x1.x * w0 + x1.y * w1 + x1.z * w2 + x1.w * w3;
        a2 += x2.x * w0 + x2.y * w1 + x2.z * w2 + x2.w * w3;
        a3 += x3.x * w0 + x3.y * w1 + x3.z * w2 + x3.w * w3;
    }
    const float bf = b_f1[c];
    h1[(size_t)(row0 + 0) * FFND + c] = gelu_(a0 + bf);
    h1[(size_t)(row0 + 1) * FFND + c] = gelu_(a1 + bf);
    h1[(size_t)(row0 + 2) * FFND + c] = gelu_(a2 + bf);
    h1[(size_t)(row0 + 3) * FFND + c] = gelu_(a3 + bf);
}

// G4+G5 fused: q = slots + h1 @ w_f2.T + b_f2 (+adjust), then (if do_qpk)
// LN(q) @ W and gq/bq scalars.  grid 256 blocks x 2 rows.
__global__ __launch_bounds__(256) void k_ffn2qpk(
    const float* __restrict__ h1, const float* __restrict__ slots,
    const float* __restrict__ w_f2T, const float* __restrict__ b_f2,
    const float* __restrict__ query,
    const float* __restrict__ g_q, const float* __restrict__ b_q,
    const float* __restrict__ W,
    const float* __restrict__ g_kv, const float* __restrict__ b_kv,
    float* __restrict__ q_out, float* __restrict__ qpk, float* __restrict__ gqbq,
    int adjust, int do_qpk) {
    const int row0 = blockIdx.x * 2;
    const int t = threadIdx.x;
    const int wave = t >> 6, lane = t & 63;
    __shared__ __align__(16) float in2[2][FFND];
    __shared__ float red[4][4];
    __shared__ __align__(16) float qn[2][EDIM];

#pragma unroll
    for (int r = 0; r < 2; ++r)
        *reinterpret_cast<float4*>(&in2[r][t * 4]) =
            *reinterpret_cast<const float4*>(h1 + (size_t)(row0 + r) * FFND + t * 4);
    __syncthreads();
    float a0 = 0.f, a1 = 0.f;
#pragma unroll 4
    for (int j = 0; j < FFND; j += 4) {
        const float4 x0 = *reinterpret_cast<const float4*>(&in2[0][j]);
        const float4 x1 = *reinterpret_cast<const float4*>(&in2[1][j]);
        const float w0 = w_f2T[(size_t)j * EDIM + t];
        const float w1 = w_f2T[(size_t)(j + 1) * EDIM + t];
        const float w2 = w_f2T[(size_t)(j + 2) * EDIM + t];
        const float w3 = w_f2T[(size_t)(j + 3) * EDIM + t];
        a0 += x0.x * w0 + x0.y * w1 + x0.z * w2 + x0.w * w3;
        a1 += x1.x * w0 + x1.y * w1 + x1.z * w2 + x1.w * w3;
    }
    const float bf = b_f2[t];
    float v0 = slots[(size_t)row0 * EDIM + t] + a0 + bf;
    float v1 = slots[(size_t)(row0 + 1) * EDIM + t] + a1 + bf;
    if (adjust) {
        const float qq0 = query[(size_t)row0 * EDIM + t];
        const float qq1 = query[(size_t)(row0 + 1) * EDIM + t];
        v0 = (v0 + qq0) - qq0;
        v1 = (v1 + qq1) - qq1;
    }
    q_out[(size_t)row0 * EDIM + t] = v0;
    q_out[(size_t)(row0 + 1) * EDIM + t] = v1;

    if (!do_qpk) return;

    {
        float a0r = v0, q0 = v0 * v0, a1r = v1, q1 = v1 * v1;
#pragma unroll
        for (int m = 1; m < 64; m <<= 1) {
            a0r += __shfl_xor(a0r, m); q0 += __shfl_xor(q0, m);
            a1r += __shfl_xor(a1r, m); q1 += __shfl_xor(q1, m);
        }
        if (lane == 0) { red[wave][0] = a0r; red[wave][1] = q0; red[wave][2] = a1r; red[wave][3] = q1; }
    }
    __syncthreads();
    {
        const float S0 = red[0][0] + red[1][0] + red[2][0] + red[3][0];
        const float Q0 = red[0][1] + red[1][1] + red[2][1] + red[3][1];
        const float S1 = red[0][2] + red[1][2] + red[2][2] + red[3][2];
        const float Q1 = red[0][3] + red[1][3] + red[2][3] + red[3][3];
        const float m0 = S0 * (1.0f / EDIM);
        const float r0 = rsqrtf(Q0 * (1.0f / EDIM) - m0 * m0 + EPS_LN);
        const float m1 = S1 * (1.0f / EDIM);
        const float r1 = rsqrtf(Q1 * (1.0f / EDIM) - m1 * m1 + EPS_LN);
        const float g = g_q[t], bb = b_q[t];
        qn[0][t] = (v0 - m0) * r0 * g + bb;
        qn[1][t] = (v1 - m1) * r1 * g + bb;
    }
    __syncthreads();
    float p0 = 0.f, p1 = 0.f;
#pragma unroll 4
    for (int j = 0; j < EDIM; j += 4) {
        const float4 x0 = *reinterpret_cast<const float4*>(&qn[0][j]);
        const float4 x1 = *reinterpret_cast<const float4*>(&qn[1][j]);
        const float w0 = W[(size_t)j * EDIM + t];
        const float w1 = W[(size_t)(j + 1) * EDIM + t];
        const float w2 = W[(size_t)(j + 2) * EDIM + t];
        const float w3 = W[(size_t)(j + 3) * EDIM + t];
        p0 += x0.x * w0 + x0.y * w1 + x0.z * w2 + x0.w * w3;
        p1 += x1.x * w0 + x1.y * w1 + x1.z * w2 + x1.w * w3;
    }
    qpk[(size_t)row0 * EDIM + t] = p0;
    qpk[(size_t)(row0 + 1) * EDIM + t] = p1;
    {
        const float gk = g_kv[t], bk = b_kv[t];
        float u0 = p0 * gk, w0 = p0 * bk, u1 = p1 * gk, w1 = p1 * bk;
#pragma unroll
        for (int m = 1; m < 64; m <<= 1) {
            u0 += __shfl_xor(u0, m); w0 += __shfl_xor(w0, m);
            u1 += __shfl_xor(u1, m); w1 += __shfl_xor(w1, m);
        }
        __syncthreads();
        if (lane == 0) { red[wave][0] = u0; red[wave][1] = w0; red[wave][2] = u1; red[wave][3] = w1; }
        __syncthreads();
        if (t == 0) {
            const int b = row0 >> 4;
            const int sl = row0 & 15;
            gqbq[b * 32 + sl] = red[0][0] + red[1][0] + red[2][0] + red[3][0];
            gqbq[b * 32 + 16 + sl] = red[0][1] + red[1][1] + red[2][1] + red[3][1];
            gqbq[b * 32 + sl + 1] = red[0][2] + red[1][2] + red[2][2] + red[3][2];
            gqbq[b * 32 + 16 + sl + 1] = red[0][3] + red[1][3] + red[2][3] + red[3][3];
        }
    }
}

extern "C" void kernel_launch(void* const* d_in, const int* in_sizes, int n_in,
                              void* d_out, int out_size, void* d_ws, size_t ws_size,
                              hipStream_t stream) {
    const float* input = (const float*)d_in[0];
    const float* query = (const float*)d_in[1];
    const float* g_kv = (const float*)d_in[2];
    const float* b_kv = (const float*)d_in[3];
    const float* w_k = (const float*)d_in[4];
    const float* w_v = (const float*)d_in[5];
    const float* g_q = (const float*)d_in[6];
    const float* b_q = (const float*)d_in[7];
    const float* w_q = (const float*)d_in[8];
    const float* w_ih = (const float*)d_in[9];
    const float* w_hh = (const float*)d_in[10];
    const float* b_ih = (const float*)d_in[11];
    const float* b_hh = (const float*)d_in[12];
    const float* g_2 = (const float*)d_in[13];
    const float* b_2 = (const float*)d_in[14];
    const float* w_f1 = (const float*)d_in[15];
    const float* b_f1 = (const float*)d_in[16];
    const float* w_f2 = (const float*)d_in[17];
    const float* b_f2 = (const float*)d_in[18];

    float* ws = (float*)d_ws;
    float* W = ws;        ws += 65536;
    float* qpk = ws;      ws += 131072;
    float* gqbq = ws;     ws += 1024;
    float* psum = ws;     ws += 32768;
    float* q_ws = ws;     ws += 131072;
    float* updates = ws;  ws += 131072;
    float* slots = ws;    ws += 131072;
    float* w_vT = ws;     ws += 65536;
    float* w_ihT = ws;    ws += 196608;
    float* w_hhT = ws;    ws += 196608;
    float* w_f1T = ws;    ws += 262144;
    float* w_f2T = ws;    ws += 262144;
    float* pacc = ws;     ws += (size_t)NB * BPB * NS * EDIM;   // 16 MB
    float* gig = pacc;                        // 512*1536 overlay (after k_upd)
    float* h1 = pacc + 786432;                // 512*1024 overlay

    float* out_q = (float*)d_out;
    float* out_attn = out_q + (size_t)NB * NS * EDIM;

    k_prep<<<256, 256, 0, stream>>>(w_q, w_k, W);
    k_tr<<<16, 256, 0, stream>>>(w_v, w_vT, 256, 256);
    k_tr<<<48, 256, 0, stream>>>(w_ih, w_ihT, 768, 256);
    k_tr<<<48, 256, 0, stream>>>(w_hh, w_hhT, 768, 256);
    k_tr<<<64, 256, 0, stream>>>(w_f1, w_f1T, 1024, 256);
    k_tr<<<64, 256, 0, stream>>>(w_f2, w_f2T, 256, 1024);
    k_qproj<<<512, 256, 0, stream>>>(query, g_q, b_q, W, g_kv, b_kv, qpk, gqbq);

    const float* qprev[3] = {query, q_ws, q_ws};
    float* qdst[3] = {q_ws, q_ws, out_q};
    const int adj[3] = {0, 1, 0};

    for (int it = 0; it < 3; ++it) {
        const bool last = (it == 2);
        if (last)
            k_bigpass<true><<<NB * BPB, 256, 0, stream>>>(input, qpk, gqbq, g_kv, pacc, psum, out_attn);
        else
            k_bigpass<false><<<NB * BPB, 256, 0, stream>>>(input, qpk, gqbq, g_kv, pacc, psum, nullptr);
        k_upd<<<256, 256, 0, stream>>>(pacc, psum, g_kv, b_kv, w_vT, updates);
        k_gates<<<768, 256, 0, stream>>>(updates, qprev[it], w_ihT, w_hhT, b_ih, b_hh, gig);
        k_gruffn1<<<512, 256, 0, stream>>>(gig, qprev[it], g_2, b_2, w_f1T, b_f1, slots, h1);
        k_ffn2qpk<<<256, 256, 0, stream>>>(h1, slots, w_f2T, b_f2, query, g_q, b_q, W,
                                           g_kv, b_kv, qdst[it], qpk, gqbq,
                                           adj[it], last ? 0 : 1);
    }
}

// Round 9
// 808.914 us; speedup vs baseline: 1.2961x; 1.0025x over previous
//
#include <hip/hip_runtime.h>
#include <math.h>

#define NB 32
#define HW 4096
#define NS 16
#define EDIM 256
#define FFND 1024
#define EPS_LN 1e-5f
#define EPS_ATTN 1e-5f
#define BPB 32            // sub-blocks per batch in bigpass
#define RPB 128           // rows per bigpass block (HW/BPB)
#define TROWS 16          // rows per barrier-tile inside bigpass

__device__ __forceinline__ float sigmoidf_(float x) { return 1.0f / (1.0f + __expf(-x)); }
__device__ __forceinline__ float gelu_(float x) {
    float x3 = x * x * x;
    return 0.5f * x * (1.0f + tanhf(0.7978845608028654f * (x + 0.044715f * x3)));
}

// W[j][c] = scale * sum_e w_q[e][j] * w_k[e][c]   (scale = 256^-0.5 = 1/16)
__global__ void k_prep(const float* __restrict__ w_q, const float* __restrict__ w_k,
                       float* __restrict__ W) {
    const int j = blockIdx.x;
    const int c = threadIdx.x;
    float acc = 0.f;
    for (int e = 0; e < EDIM; ++e)
        acc += w_q[e * EDIM + j] * w_k[e * EDIM + c];
    W[j * EDIM + c] = acc * 0.0625f;
}

// Tiled transpose: src[R][C] -> dst[C][R].  R,C multiples of 64. 64x64 tiles.
__global__ __launch_bounds__(256) void k_tr(const float* __restrict__ src,
                                            float* __restrict__ dst, int R, int C) {
    __shared__ float tile[64][65];
    const int tilesC = C >> 6;
    const int tR = (blockIdx.x / tilesC) << 6;
    const int tC = (blockIdx.x % tilesC) << 6;
    const int t = threadIdx.x;
    {
        const int r = t >> 2;
        const int c0 = (t & 3) << 4;
#pragma unroll
        for (int i = 0; i < 16; i += 4) {
            const float4 v = *reinterpret_cast<const float4*>(src + (size_t)(tR + r) * C + tC + c0 + i);
            tile[r][c0 + i] = v.x; tile[r][c0 + i + 1] = v.y;
            tile[r][c0 + i + 2] = v.z; tile[r][c0 + i + 3] = v.w;
        }
    }
    __syncthreads();
    {
        const int c = t >> 2;
        const int r0 = (t & 3) << 4;
#pragma unroll
        for (int i = 0; i < 16; ++i)
            dst[(size_t)(tC + c) * R + tR + r0 + i] = tile[r0 + i][c];
    }
}

// Iteration-0 only: qn = LN(query_row); qpk = qn @ W; gq/bq scalars.
__global__ void k_qproj(const float* __restrict__ qsrc, const float* __restrict__ g_q,
                        const float* __restrict__ b_q, const float* __restrict__ W,
                        const float* __restrict__ g_kv, const float* __restrict__ b_kv,
                        float* __restrict__ qpk, float* __restrict__ gqbq) {
    const int row = blockIdx.x;   // 0..511  (= b*16 + s)
    const int t = threadIdx.x;
    __shared__ float qn[EDIM];
    __shared__ float red[16];
    const float v = qsrc[(size_t)row * EDIM + t];
    float s = v, ss = v * v;
#pragma unroll
    for (int m = 1; m < 64; m <<= 1) { s += __shfl_xor(s, m); ss += __shfl_xor(ss, m); }
    const int wave = t >> 6, lane = t & 63;
    if (lane == 0) { red[wave] = s; red[8 + wave] = ss; }
    __syncthreads();
    const float st = red[0] + red[1] + red[2] + red[3];
    const float sst = red[8] + red[9] + red[10] + red[11];
    const float mean = st * (1.0f / EDIM);
    const float rstd = rsqrtf(sst * (1.0f / EDIM) - mean * mean + EPS_LN);
    qn[t] = (v - mean) * rstd * g_q[t] + b_q[t];
    __syncthreads();
    float acc = 0.f;
    for (int j = 0; j < EDIM; ++j)
        acc += qn[j] * W[j * EDIM + t];
    qpk[(size_t)row * EDIM + t] = acc;
    float u = acc * g_kv[t];
    float w2 = acc * b_kv[t];
#pragma unroll
    for (int m = 1; m < 64; m <<= 1) { u += __shfl_xor(u, m); w2 += __shfl_xor(w2, m); }
    __syncthreads();
    if (lane == 0) { red[wave] = u; red[8 + wave] = w2; }
    __syncthreads();
    if (t == 0) {
        const int b = row >> 4, sl = row & 15;
        gqbq[b * 32 + sl] = red[0] + red[1] + red[2] + red[3];
        gqbq[b * 32 + 16 + sl] = red[8] + red[9] + red[10] + red[11];
    }
}

// Streaming pass v6b: LDS-staged 16-row tiles, grid 1024 (4 blocks/CU), LDS ~34 KB.
// waves_per_eu pinned to (4,4): VGPR cap 128, stops the compiler squeezing to 64
// VGPRs and spilling acc[][]+p[] to scratch (r8: 497 MB scratch WRITE at VGPR=64).
template <bool LAST>
__global__ __launch_bounds__(256)
__attribute__((amdgpu_waves_per_eu(4, 4))) void k_bigpass(
    const float* __restrict__ input, const float* __restrict__ qpk,
    const float* __restrict__ gqbq, const float* __restrict__ g_kv,
    float* __restrict__ pacc, float* __restrict__ psum, float* __restrict__ attn_out) {
    const int b = blockIdx.x >> 5;        // /BPB
    const int sub = blockIdx.x & 31;      // %BPB
    const int t = threadIdx.x;
    const int w = t >> 6;
    const int lane = t & 63;
    const int g = t >> 4;      // row in tile (0..15)
    const int j = t & 15;      // channel 16th within row

    __shared__ __align__(16) float G[NS][EDIM];        // 16 KB
    __shared__ __align__(16) float stage[TROWS][264];  // 16.5 KB padded
    __shared__ __align__(16) float wrec[TROWS][20];    // attn[16], rstd, rstd*mean
    __shared__ float gqbq_s[2][NS];

    // prologue: G = g_kv (broadcast over s) * qpk[b]
#pragma unroll
    for (int i = 0; i < 4; ++i) {
        const int idx = i * 1024 + t * 4;
        const float4 qv = *reinterpret_cast<const float4*>(qpk + (size_t)b * 4096 + idx);
        const float4 gv = *reinterpret_cast<const float4*>(g_kv + (idx & 255));
        *reinterpret_cast<float4*>(&G[0][0] + idx) =
            make_float4(qv.x * gv.x, qv.y * gv.y, qv.z * gv.z, qv.w * gv.w);
    }
    if (t < 32) gqbq_s[t >> 4][t & 15] = gqbq[b * 32 + t];
    __syncthreads();

    float acc[4][4];
    float S[4], A[4];
#pragma unroll
    for (int si = 0; si < 4; ++si) {
        acc[si][0] = acc[si][1] = acc[si][2] = acc[si][3] = 0.f;
        S[si] = 0.f; A[si] = 0.f;
    }

    const int rowbase = sub * RPB;
#pragma unroll 1
    for (int tt = 0; tt < RPB / TROWS; ++tt) {
        const int grow = rowbase + tt * TROWS + g;
        const float* xa = input + ((size_t)b * HW + grow) * EDIM;

        // ---- phase A ----
        float p[NS];
#pragma unroll
        for (int s = 0; s < NS; ++s) p[s] = 0.f;
        float s1 = 0.f, s2 = 0.f;
#pragma unroll
        for (int c = 0; c < 4; ++c) {
            const int off = (c * 16 + j) * 4;
            const float4 x = *reinterpret_cast<const float4*>(xa + off);
            *reinterpret_cast<float4*>(&stage[g][off]) = x;
            s1 += x.x + x.y + x.z + x.w;
            s2 += x.x * x.x + x.y * x.y + x.z * x.z + x.w * x.w;
#pragma unroll
            for (int s = 0; s < NS; ++s) {
                const float4 gg = *reinterpret_cast<const float4*>(&G[s][off]);
                p[s] += x.x * gg.x + x.y * gg.y + x.z * gg.z + x.w * gg.w;
            }
        }
#pragma unroll
        for (int m = 1; m < 16; m <<= 1) {
            s1 += __shfl_xor(s1, m); s2 += __shfl_xor(s2, m);
#pragma unroll
            for (int s = 0; s < NS; ++s) p[s] += __shfl_xor(p[s], m);
        }
        const float mean = s1 * (1.0f / EDIM);
        const float rstd = rsqrtf(s2 * (1.0f / EDIM) - mean * mean + EPS_LN);
        float mx = -1e30f;
#pragma unroll
        for (int s = 0; s < NS; ++s) {
            p[s] = rstd * (p[s] - mean * gqbq_s[0][s]) + gqbq_s[1][s];
            mx = fmaxf(mx, p[s]);
        }
        float tot = 0.f;
#pragma unroll
        for (int s = 0; s < NS; ++s) { p[s] = __expf(p[s] - mx); tot += p[s]; }
        const float inv = 1.0f / tot;
#pragma unroll
        for (int s = 0; s < NS; ++s) p[s] *= inv;

        if (j == 0) {
#pragma unroll
            for (int sq = 0; sq < 4; ++sq)
                *reinterpret_cast<float4*>(&wrec[g][sq * 4]) =
                    make_float4(p[sq * 4], p[sq * 4 + 1], p[sq * 4 + 2], p[sq * 4 + 3]);
            wrec[g][16] = rstd;
            wrec[g][17] = rstd * mean;
            if (LAST) {
#pragma unroll
                for (int s = 0; s < NS; ++s)
                    attn_out[((size_t)(b * NS + s)) * HW + grow] = p[s];
            }
        }
        __syncthreads();

        // ---- phase B: wave w accumulates slots 4w..4w+3 from staged x ----
        {
            const int ch = lane * 4;
            const int sbase = w * 4;
#pragma unroll
            for (int r = 0; r < TROWS; ++r) {
                const float4 xv = *reinterpret_cast<const float4*>(&stage[r][ch]);
                const float4 at = *reinterpret_cast<const float4*>(&wrec[r][sbase]);
                const float rr = wrec[r][16];
                const float rm = wrec[r][17];
                float wg;
                wg = at.x * rr;
                acc[0][0] += wg * xv.x; acc[0][1] += wg * xv.y;
                acc[0][2] += wg * xv.z; acc[0][3] += wg * xv.w;
                S[0] += at.x; A[0] += at.x * rm;
                wg = at.y * rr;
                acc[1][0] += wg * xv.x; acc[1][1] += wg * xv.y;
                acc[1][2] += wg * xv.z; acc[1][3] += wg * xv.w;
                S[1] += at.y; A[1] += at.y * rm;
                wg = at.z * rr;
                acc[2][0] += wg * xv.x; acc[2][1] += wg * xv.y;
                acc[2][2] += wg * xv.z; acc[2][3] += wg * xv.w;
                S[2] += at.z; A[2] += at.z * rm;
                wg = at.w * rr;
                acc[3][0] += wg * xv.x; acc[3][1] += wg * xv.y;
                acc[3][2] += wg * xv.z; acc[3][3] += wg * xv.w;
                S[3] += at.w; A[3] += at.w * rm;
            }
        }
        __syncthreads();
    }

    // epilogue: each wave writes its own 4 slots
#pragma unroll
    for (int si = 0; si < 4; ++si) {
        *reinterpret_cast<float4*>(
            pacc + ((size_t)blockIdx.x * NS + w * 4 + si) * EDIM + lane * 4) =
            make_float4(acc[si][0], acc[si][1], acc[si][2], acc[si][3]);
    }
    if (lane == 0) {
#pragma unroll
        for (int si = 0; si < 4; ++si) {
            psum[blockIdx.x * 32 + w * 4 + si] = S[si];
            psum[blockIdx.x * 32 + 16 + w * 4 + si] = A[si];
        }
    }
}

// G1: partial reduce + ub + updates = ub @ w_v.T.  grid 256: (rt 0..127) x (ct 0..1)
__global__ __launch_bounds__(256) void k_upd(
    const float* __restrict__ pacc, const float* __restrict__ psum,
    const float* __restrict__ g_kv, const float* __restrict__ b_kv,
    const float* __restrict__ w_vT, float* __restrict__ updates) {
    const int rt = blockIdx.x >> 1;
    const int ct = blockIdx.x & 1;
    const int row0 = rt * 4;
    const int b = row0 >> 4;
    const int s0 = row0 & 15;
    const int t = threadIdx.x;
    __shared__ __align__(16) float ub[4][EDIM];
    __shared__ float sSA[4][2];

    if (t < 8) {
        const int r = t & 3;
        const int isA = t >> 2;
        float v = 0.f;
        for (int p = 0; p < BPB; ++p)
            v += psum[(b * BPB + p) * 32 + isA * 16 + s0 + r];
        sSA[r][isA] = v;
    }
    __syncthreads();
#pragma unroll
    for (int r = 0; r < 4; ++r) {
        float V = 0.f;
        for (int p = 0; p < BPB; ++p)
            V += pacc[((size_t)(b * BPB + p) * NS + s0 + r) * EDIM + t];
        const float Sv = sSA[r][0], Av = sSA[r][1];
        ub[r][t] = (g_kv[t] * (V - Av) + b_kv[t] * Sv) / (Sv + EPS_ATTN);
    }
    __syncthreads();

    const int c = ct * 128 + (t & 127);
    const int half = t >> 7;       // 2 rows per thread
    const float* u0 = ub[2 * half];
    const float* u1 = ub[2 * half + 1];
    float a0 = 0.f, a1 = 0.f;
#pragma unroll 4
    for (int j = 0; j < EDIM; j += 4) {
        const float4 x0 = *reinterpret_cast<const float4*>(u0 + j);
        const float4 x1 = *reinterpret_cast<const float4*>(u1 + j);
        const float w0 = w_vT[(size_t)j * EDIM + c];
        const float w1 = w_vT[(size_t)(j + 1) * EDIM + c];
        const float w2 = w_vT[(size_t)(j + 2) * EDIM + c];
        const float w3 = w_vT[(size_t)(j + 3) * EDIM + c];
        a0 += x0.x * w0 + x0.y * w1 + x0.z * w2 + x0.w * w3;
        a1 += x1.x * w0 + x1.y * w1 + x1.z * w2 + x1.w * w3;
    }
    updates[(size_t)(row0 + 2 * half) * EDIM + c] = a0;
    updates[(size_t)(row0 + 2 * half + 1) * EDIM + c] = a1;
}

// G2a: gi = upd @ w_ih.T + b_ih (ct 0..2), gh = qprev @ w_hh.T + b_hh (ct 3..5).
// grid 768: rt = bid/6 (4 rows), ct = bid%6 (256 cols).
__global__ __launch_bounds__(256) void k_gates(
    const float* __restrict__ updates, const float* __restrict__ qprev,
    const float* __restrict__ w_ihT, const float* __restrict__ w_hhT,
    const float* __restrict__ b_ih, const float* __restrict__ b_hh,
    float* __restrict__ gig) {
    const int rt = blockIdx.x / 6;
    const int ct = blockIdx.x % 6;
    const int row0 = rt * 4;
    const int t = threadIdx.x;
    const bool ih = ct < 3;
    const int lc = (ih ? ct : ct - 3) * 256 + t;   // 0..767
    const float* __restrict__ src = ih ? updates : qprev;
    const float* __restrict__ wT = ih ? w_ihT : w_hhT;

    __shared__ __align__(16) float in4[4][EDIM];
#pragma unroll
    for (int r = 0; r < 4; ++r)
        in4[r][t] = src[(size_t)(row0 + r) * EDIM + t];
    __syncthreads();

    float a0 = 0.f, a1 = 0.f, a2 = 0.f, a3 = 0.f;
#pragma unroll 4
    for (int j = 0; j < EDIM; j += 4) {
        const float4 x0 = *reinterpret_cast<const float4*>(&in4[0][j]);
        const float4 x1 = *reinterpret_cast<const float4*>(&in4[1][j]);
        const float4 x2 = *reinterpret_cast<const float4*>(&in4[2][j]);
        const float4 x3 = *reinterpret_cast<const float4*>(&in4[3][j]);
        const float w0 = wT[(size_t)j * 768 + lc];
        const float w1 = wT[(size_t)(j + 1) * 768 + lc];
        const float w2 = wT[(size_t)(j + 2) * 768 + lc];
        const float w3 = wT[(size_t)(j + 3) * 768 + lc];
        a0 += x0.x * w0 + x0.y * w1 + x0.z * w2 + x0.w * w3;
        a1 += x1.x * w0 + x1.y * w1 + x1.z * w2 + x1.w * w3;
        a2 += x2.x * w0 + x2.y * w1 + x2.z * w2 + x2.w * w3;
        a3 += x3.x * w0 + x3.y * w1 + x3.z * w2 + x3.w * w3;
    }
    const float bias = ih ? b_ih[lc] : b_hh[lc];
    const int gcol = ih ? lc : 768 + lc;
    gig[(size_t)(row0 + 0) * 1536 + gcol] = a0 + bias;
    gig[(size_t)(row0 + 1) * 1536 + gcol] = a1 + bias;
    gig[(size_t)(row0 + 2) * 1536 + gcol] = a2 + bias;
    gig[(size_t)(row0 + 3) * 1536 + gcol] = a3 + bias;
}

// G2b+G3 fused: recompute GRU pointwise + LN for this block's 4 rows, then
// h1 slice = gelu(ln2 @ w_f1T[:, ct*256..+255] + b_f1).
// grid 512: rt = bid>>2 (4 rows), ct = bid&3 (256 cols).
__global__ __launch_bounds__(256) void k_gruffn1(
    const float* __restrict__ gig, const float* __restrict__ qprev,
    const float* __restrict__ g_2, const float* __restrict__ b_2,
    const float* __restrict__ w_f1T, const float* __restrict__ b_f1,
    float* __restrict__ slots, float* __restrict__ h1) {
    const int rt = blockIdx.x >> 2;
    const int ct = blockIdx.x & 3;
    const int row0 = rt * 4;
    const int t = threadIdx.x;
    const int wave = t >> 6, lane = t & 63;
    __shared__ __align__(16) float ln2[4][EDIM];
    __shared__ float red[4][8];

    float sl[4];
#pragma unroll
    for (int r = 0; r < 4; ++r) {
        const size_t base = (size_t)(row0 + r) * 1536;
        const float ir = gig[base + t];
        const float iz = gig[base + 256 + t];
        const float inn = gig[base + 512 + t];
        const float hr = gig[base + 768 + t];
        const float hz = gig[base + 1024 + t];
        const float hn = gig[base + 1280 + t];
        const float h = qprev[(size_t)(row0 + r) * EDIM + t];
        const float rg = sigmoidf_(ir + hr);
        const float z = sigmoidf_(iz + hz);
        const float n = tanhf(inn + rg * hn);
        sl[r] = (1.0f - z) * n + z * h;
    }
    if (ct == 0) {
#pragma unroll
        for (int r = 0; r < 4; ++r)
            slots[(size_t)(row0 + r) * EDIM + t] = sl[r];
    }
    {
        float a[4], qq[4];
#pragma unroll
        for (int r = 0; r < 4; ++r) { a[r] = sl[r]; qq[r] = sl[r] * sl[r]; }
#pragma unroll
        for (int m = 1; m < 64; m <<= 1) {
#pragma unroll
            for (int r = 0; r < 4; ++r) {
                a[r] += __shfl_xor(a[r], m);
                qq[r] += __shfl_xor(qq[r], m);
            }
        }
        if (lane == 0) {
#pragma unroll
            for (int r = 0; r < 4; ++r) { red[wave][r] = a[r]; red[wave][4 + r] = qq[r]; }
        }
    }
    __syncthreads();
    {
        const float g = g_2[t], bb = b_2[t];
#pragma unroll
        for (int r = 0; r < 4; ++r) {
            const float Sv = red[0][r] + red[1][r] + red[2][r] + red[3][r];
            const float Qv = red[0][4 + r] + red[1][4 + r] + red[2][4 + r] + red[3][4 + r];
            const float mn = Sv * (1.0f / EDIM);
            const float rs = rsqrtf(Qv * (1.0f / EDIM) - mn * mn + EPS_LN);
            ln2[r][t] = (sl[r] - mn) * rs * g + bb;
        }
    }
    __syncthreads();

    const int c = ct * 256 + t;
    float a0 = 0.f, a1 = 0.f, a2 = 0.f, a3 = 0.f;
#pragma unroll 4
    for (int j = 0; j < EDIM; j += 4) {
        const float4 x0 = *reinterpret_cast<const float4*>(&ln2[0][j]);
        const float4 x1 = *reinterpret_cast<const float4*>(&ln2[1][j]);
        const float4 x2 = *reinterpret_cast<const float4*>(&ln2[2][j]);
        const float4 x3 = *reinterpret_cast<const float4*>(&ln2[3][j]);
        const float w0 = w_f1T[(size_t)j * FFND + c];
        const float w1 = w_f1T[(size_t)(j + 1) * FFND + c];
        const float w2 = w_f1T[(size_t)(j + 2) * FFND + c];
        const float w3 = w_f1T[(size_t)(j + 3) * FFND + c];
        a0 += x0.x * w0 + x0.y * w1 + x0.z * w2 + x0.w * w3;
        a1 += x1.x * w0 + x1.y * w1 + x1.z * w2 + x1.w * w3;
        a2 += x2.x * w0 + x2.y * w1 + x2.z * w2 + x2.w * w3;
        a3 += x3.x * w0 + x3.y * w1 + x3.z * w2 + x3.w * w3;
    }
    const float bf = b_f1[c];
    h1[(size_t)(row0 + 0) * FFND + c] = gelu_(a0 + bf);
    h1[(size_t)(row0 + 1) * FFND + c] = gelu_(a1 + bf);
    h1[(size_t)(row0 + 2) * FFND + c] = gelu_(a2 + bf);
    h1[(size_t)(row0 + 3) * FFND + c] = gelu_(a3 + bf);
}

// G4+G5 fused: q = slots + h1 @ w_f2.T + b_f2 (+adjust), then (if do_qpk)
// LN(q) @ W and gq/bq scalars.  grid 256 blocks x 2 rows.
__global__ __launch_bounds__(256) void k_ffn2qpk(
    const float* __restrict__ h1, const float* __restrict__ slots,
    const float* __restrict__ w_f2T, const float* __restrict__ b_f2,
    const float* __restrict__ query,
    const float* __restrict__ g_q, const float* __restrict__ b_q,
    const float* __restrict__ W,
    const float* __restrict__ g_kv, const float* __restrict__ b_kv,
    float* __restrict__ q_out, float* __restrict__ qpk, float* __restrict__ gqbq,
    int adjust, int do_qpk) {
    const int row0 = blockIdx.x * 2;
    const int t = threadIdx.x;
    const int wave = t >> 6, lane = t & 63;
    __shared__ __align__(16) float in2[2][FFND];
    __shared__ float red[4][4];
    __shared__ __align__(16) float qn[2][EDIM];

#pragma unroll
    for (int r = 0; r < 2; ++r)
        *reinterpret_cast<float4*>(&in2[r][t * 4]) =
            *reinterpret_cast<const float4*>(h1 + (size_t)(row0 + r) * FFND + t * 4);
    __syncthreads();
    float a0 = 0.f, a1 = 0.f;
#pragma unroll 4
    for (int j = 0; j < FFND; j += 4) {
        const float4 x0 = *reinterpret_cast<const float4*>(&in2[0][j]);
        const float4 x1 = *reinterpret_cast<const float4*>(&in2[1][j]);
        const float w0 = w_f2T[(size_t)j * EDIM + t];
        const float w1 = w_f2T[(size_t)(j + 1) * EDIM + t];
        const float w2 = w_f2T[(size_t)(j + 2) * EDIM + t];
        const float w3 = w_f2T[(size_t)(j + 3) * EDIM + t];
        a0 += x0.x * w0 + x0.y * w1 + x0.z * w2 + x0.w * w3;
        a1 += x1.x * w0 + x1.y * w1 + x1.z * w2 + x1.w * w3;
    }
    const float bf = b_f2[t];
    float v0 = slots[(size_t)row0 * EDIM + t] + a0 + bf;
    float v1 = slots[(size_t)(row0 + 1) * EDIM + t] + a1 + bf;
    if (adjust) {
        const float qq0 = query[(size_t)row0 * EDIM + t];
        const float qq1 = query[(size_t)(row0 + 1) * EDIM + t];
        v0 = (v0 + qq0) - qq0;
        v1 = (v1 + qq1) - qq1;
    }
    q_out[(size_t)row0 * EDIM + t] = v0;
    q_out[(size_t)(row0 + 1) * EDIM + t] = v1;

    if (!do_qpk) return;

    {
        float a0r = v0, q0 = v0 * v0, a1r = v1, q1 = v1 * v1;
#pragma unroll
        for (int m = 1; m < 64; m <<= 1) {
            a0r += __shfl_xor(a0r, m); q0 += __shfl_xor(q0, m);
            a1r += __shfl_xor(a1r, m); q1 += __shfl_xor(q1, m);
        }
        if (lane == 0) { red[wave][0] = a0r; red[wave][1] = q0; red[wave][2] = a1r; red[wave][3] = q1; }
    }
    __syncthreads();
    {
        const float S0 = red[0][0] + red[1][0] + red[2][0] + red[3][0];
        const float Q0 = red[0][1] + red[1][1] + red[2][1] + red[3][1];
        const float S1 = red[0][2] + red[1][2] + red[2][2] + red[3][2];
        const float Q1 = red[0][3] + red[1][3] + red[2][3] + red[3][3];
        const float m0 = S0 * (1.0f / EDIM);
        const float r0 = rsqrtf(Q0 * (1.0f / EDIM) - m0 * m0 + EPS_LN);
        const float m1 = S1 * (1.0f / EDIM);
        const float r1 = rsqrtf(Q1 * (1.0f / EDIM) - m1 * m1 + EPS_LN);
        const float g = g_q[t], bb = b_q[t];
        qn[0][t] = (v0 - m0) * r0 * g + bb;
        qn[1][t] = (v1 - m1) * r1 * g + bb;
    }
    __syncthreads();
    float p0 = 0.f, p1 = 0.f;
#pragma unroll 4
    for (int j = 0; j < EDIM; j += 4) {
        const float4 x0 = *reinterpret_cast<const float4*>(&qn[0][j]);
        const float4 x1 = *reinterpret_cast<const float4*>(&qn[1][j]);
        const float w0 = W[(size_t)j * EDIM + t];
        const float w1 = W[(size_t)(j + 1) * EDIM + t];
        const float w2 = W[(size_t)(j + 2) * EDIM + t];
        const float w3 = W[(size_t)(j + 3) * EDIM + t];
        p0 += x0.x * w0 + x0.y * w1 + x0.z * w2 + x0.w * w3;
        p1 += x1.x * w0 + x1.y * w1 + x1.z * w2 + x1.w * w3;
    }
    qpk[(size_t)row0 * EDIM + t] = p0;
    qpk[(size_t)(row0 + 1) * EDIM + t] = p1;
    {
        const float gk = g_kv[t], bk = b_kv[t];
        float u0 = p0 * gk, w0 = p0 * bk, u1 = p1 * gk, w1 = p1 * bk;
#pragma unroll
        for (int m = 1; m < 64; m <<= 1) {
            u0 += __shfl_xor(u0, m); w0 += __shfl_xor(w0, m);
            u1 += __shfl_xor(u1, m); w1 += __shfl_xor(w1, m);
        }
        __syncthreads();
        if (lane == 0) { red[wave][0] = u0; red[wave][1] = w0; red[wave][2] = u1; red[wave][3] = w1; }
        __syncthreads();
        if (t == 0) {
            const int b = row0 >> 4;
            const int sl = row0 & 15;
            gqbq[b * 32 + sl] = red[0][0] + red[1][0] + red[2][0] + red[3][0];
            gqbq[b * 32 + 16 + sl] = red[0][1] + red[1][1] + red[2][1] + red[3][1];
            gqbq[b * 32 + sl + 1] = red[0][2] + red[1][2] + red[2][2] + red[3][2];
            gqbq[b * 32 + 16 + sl + 1] = red[0][3] + red[1][3] + red[2][3] + red[3][3];
        }
    }
}

extern "C" void kernel_launch(void* const* d_in, const int* in_sizes, int n_in,
                              void* d_out, int out_size, void* d_ws, size_t ws_size,
                              hipStream_t stream) {
    const float* input = (const float*)d_in[0];
    const float* query = (const float*)d_in[1];
    const float* g_kv = (const float*)d_in[2];
    const float* b_kv = (const float*)d_in[3];
    const float* w_k = (const float*)d_in[4];
    const float* w_v = (const float*)d_in[5];
    const float* g_q = (const float*)d_in[6];
    const float* b_q = (const float*)d_in[7];
    const float* w_q = (const float*)d_in[8];
    const float* w_ih = (const float*)d_in[9];
    const float* w_hh = (const float*)d_in[10];
    const float* b_ih = (const float*)d_in[11];
    const float* b_hh = (const float*)d_in[12];
    const float* g_2 = (const float*)d_in[13];
    const float* b_2 = (const float*)d_in[14];
    const float* w_f1 = (const float*)d_in[15];
    const float* b_f1 = (const float*)d_in[16];
    const float* w_f2 = (const float*)d_in[17];
    const float* b_f2 = (const float*)d_in[18];

    float* ws = (float*)d_ws;
    float* W = ws;        ws += 65536;
    float* qpk = ws;      ws += 131072;
    float* gqbq = ws;     ws += 1024;
    float* psum = ws;     ws += 32768;
    float* q_ws = ws;     ws += 131072;
    float* updates = ws;  ws += 131072;
    float* slots = ws;    ws += 131072;
    float* w_vT = ws;     ws += 65536;
    float* w_ihT = ws;    ws += 196608;
    float* w_hhT = ws;    ws += 196608;
    float* w_f1T = ws;    ws += 262144;
    float* w_f2T = ws;    ws += 262144;
    float* pacc = ws;     ws += (size_t)NB * BPB * NS * EDIM;   // 16 MB
    float* gig = pacc;                        // 512*1536 overlay (after k_upd)
    float* h1 = pacc + 786432;                // 512*1024 overlay

    float* out_q = (float*)d_out;
    float* out_attn = out_q + (size_t)NB * NS * EDIM;

    k_prep<<<256, 256, 0, stream>>>(w_q, w_k, W);
    k_tr<<<16, 256, 0, stream>>>(w_v, w_vT, 256, 256);
    k_tr<<<48, 256, 0, stream>>>(w_ih, w_ihT, 768, 256);
    k_tr<<<48, 256, 0, stream>>>(w_hh, w_hhT, 768, 256);
    k_tr<<<64, 256, 0, stream>>>(w_f1, w_f1T, 1024, 256);
    k_tr<<<64, 256, 0, stream>>>(w_f2, w_f2T, 256, 1024);
    k_qproj<<<512, 256, 0, stream>>>(query, g_q, b_q, W, g_kv, b_kv, qpk, gqbq);

    const float* qprev[3] = {query, q_ws, q_ws};
    float* qdst[3] = {q_ws, q_ws, out_q};
    const int adj[3] = {0, 1, 0};

    for (int it = 0; it < 3; ++it) {
        const bool last = (it == 2);
        if (last)
            k_bigpass<true><<<NB * BPB, 256, 0, stream>>>(input, qpk, gqbq, g_kv, pacc, psum, out_attn);
        else
            k_bigpass<false><<<NB * BPB, 256, 0, stream>>>(input, qpk, gqbq, g_kv, pacc, psum, nullptr);
        k_upd<<<256, 256, 0, stream>>>(pacc, psum, g_kv, b_kv, w_vT, updates);
        k_gates<<<768, 256, 0, stream>>>(updates, qprev[it], w_ihT, w_hhT, b_ih, b_hh, gig);
        k_gruffn1<<<512, 256, 0, stream>>>(gig, qprev[it], g_2, b_2, w_f1T, b_f1, slots, h1);
        k_ffn2qpk<<<256, 256, 0, stream>>>(h1, slots, w_f2T, b_f2, query, g_q, b_q, W,
                                           g_kv, b_kv, qdst[it], qpk, gqbq,
                                           adj[it], last ? 0 : 1);
    }
}

// Round 10
// 543.846 us; speedup vs baseline: 1.9278x; 1.4874x over previous
//
#include <hip/hip_runtime.h>
#include <math.h>

#define NB 32
#define HW 4096
#define NS 16
#define EDIM 256
#define FFND 1024
#define EPS_LN 1e-5f
#define EPS_ATTN 1e-5f
#define BPB 32            // sub-blocks per batch in bigpass
#define RPB 128           // rows per bigpass block (HW/BPB)
#define TROWS 16          // rows per barrier-tile inside bigpass

__device__ __forceinline__ float sigmoidf_(float x) { return 1.0f / (1.0f + __expf(-x)); }
__device__ __forceinline__ float gelu_(float x) {
    float x3 = x * x * x;
    return 0.5f * x * (1.0f + tanhf(0.7978845608028654f * (x + 0.044715f * x3)));
}

// W[j][c] = scale * sum_e w_q[e][j] * w_k[e][c]   (scale = 256^-0.5 = 1/16)
__global__ void k_prep(const float* __restrict__ w_q, const float* __restrict__ w_k,
                       float* __restrict__ W) {
    const int j = blockIdx.x;
    const int c = threadIdx.x;
    float acc = 0.f;
    for (int e = 0; e < EDIM; ++e)
        acc += w_q[e * EDIM + j] * w_k[e * EDIM + c];
    W[j * EDIM + c] = acc * 0.0625f;
}

// Tiled transpose: src[R][C] -> dst[C][R].  R,C multiples of 64. 64x64 tiles.
__global__ __launch_bounds__(256) void k_tr(const float* __restrict__ src,
                                            float* __restrict__ dst, int R, int C) {
    __shared__ float tile[64][65];
    const int tilesC = C >> 6;
    const int tR = (blockIdx.x / tilesC) << 6;
    const int tC = (blockIdx.x % tilesC) << 6;
    const int t = threadIdx.x;
    {
        const int r = t >> 2;
        const int c0 = (t & 3) << 4;
#pragma unroll
        for (int i = 0; i < 16; i += 4) {
            const float4 v = *reinterpret_cast<const float4*>(src + (size_t)(tR + r) * C + tC + c0 + i);
            tile[r][c0 + i] = v.x; tile[r][c0 + i + 1] = v.y;
            tile[r][c0 + i + 2] = v.z; tile[r][c0 + i + 3] = v.w;
        }
    }
    __syncthreads();
    {
        const int c = t >> 2;
        const int r0 = (t & 3) << 4;
#pragma unroll
        for (int i = 0; i < 16; ++i)
            dst[(size_t)(tC + c) * R + tR + r0 + i] = tile[r0 + i][c];
    }
}

// Iteration-0 only: qn = LN(query_row); qpk = qn @ W; gq/bq scalars.
__global__ void k_qproj(const float* __restrict__ qsrc, const float* __restrict__ g_q,
                        const float* __restrict__ b_q, const float* __restrict__ W,
                        const float* __restrict__ g_kv, const float* __restrict__ b_kv,
                        float* __restrict__ qpk, float* __restrict__ gqbq) {
    const int row = blockIdx.x;   // 0..511  (= b*16 + s)
    const int t = threadIdx.x;
    __shared__ float qn[EDIM];
    __shared__ float red[16];
    const float v = qsrc[(size_t)row * EDIM + t];
    float s = v, ss = v * v;
#pragma unroll
    for (int m = 1; m < 64; m <<= 1) { s += __shfl_xor(s, m); ss += __shfl_xor(ss, m); }
    const int wave = t >> 6, lane = t & 63;
    if (lane == 0) { red[wave] = s; red[8 + wave] = ss; }
    __syncthreads();
    const float st = red[0] + red[1] + red[2] + red[3];
    const float sst = red[8] + red[9] + red[10] + red[11];
    const float mean = st * (1.0f / EDIM);
    const float rstd = rsqrtf(sst * (1.0f / EDIM) - mean * mean + EPS_LN);
    qn[t] = (v - mean) * rstd * g_q[t] + b_q[t];
    __syncthreads();
    float acc = 0.f;
    for (int j = 0; j < EDIM; ++j)
        acc += qn[j] * W[j * EDIM + t];
    qpk[(size_t)row * EDIM + t] = acc;
    float u = acc * g_kv[t];
    float w2 = acc * b_kv[t];
#pragma unroll
    for (int m = 1; m < 64; m <<= 1) { u += __shfl_xor(u, m); w2 += __shfl_xor(w2, m); }
    __syncthreads();
    if (lane == 0) { red[wave] = u; red[8 + wave] = w2; }
    __syncthreads();
    if (t == 0) {
        const int b = row >> 4, sl = row & 15;
        gqbq[b * 32 + sl] = red[0] + red[1] + red[2] + red[3];
        gqbq[b * 32 + 16 + sl] = red[8] + red[9] + red[10] + red[11];
    }
}

// Streaming pass v6c: LDS-staged 16-row tiles, grid 1024, LDS ~34 KB (4 blocks/CU).
// launch_bounds min-waves = 2: empirically (r5 vs r7/r8/r9) hint=2 -> VGPR 80, no
// scratch spill; hint=4 / waves_per_eu(4,4) -> VGPR 64 + ~480 MB scratch traffic.
template <bool LAST>
__global__ __launch_bounds__(256, 2) void k_bigpass(
    const float* __restrict__ input, const float* __restrict__ qpk,
    const float* __restrict__ gqbq, const float* __restrict__ g_kv,
    float* __restrict__ pacc, float* __restrict__ psum, float* __restrict__ attn_out) {
    const int b = blockIdx.x >> 5;        // /BPB
    const int sub = blockIdx.x & 31;      // %BPB
    const int t = threadIdx.x;
    const int w = t >> 6;
    const int lane = t & 63;
    const int g = t >> 4;      // row in tile (0..15)
    const int j = t & 15;      // channel 16th within row

    __shared__ __align__(16) float G[NS][EDIM];        // 16 KB
    __shared__ __align__(16) float stage[TROWS][264];  // 16.5 KB padded
    __shared__ __align__(16) float wrec[TROWS][20];    // attn[16], rstd, rstd*mean
    __shared__ float gqbq_s[2][NS];

    // prologue: G = g_kv (broadcast over s) * qpk[b]
#pragma unroll
    for (int i = 0; i < 4; ++i) {
        const int idx = i * 1024 + t * 4;
        const float4 qv = *reinterpret_cast<const float4*>(qpk + (size_t)b * 4096 + idx);
        const float4 gv = *reinterpret_cast<const float4*>(g_kv + (idx & 255));
        *reinterpret_cast<float4*>(&G[0][0] + idx) =
            make_float4(qv.x * gv.x, qv.y * gv.y, qv.z * gv.z, qv.w * gv.w);
    }
    if (t < 32) gqbq_s[t >> 4][t & 15] = gqbq[b * 32 + t];
    __syncthreads();

    float acc[4][4];
    float S[4], A[4];
#pragma unroll
    for (int si = 0; si < 4; ++si) {
        acc[si][0] = acc[si][1] = acc[si][2] = acc[si][3] = 0.f;
        S[si] = 0.f; A[si] = 0.f;
    }

    const int rowbase = sub * RPB;
#pragma unroll 1
    for (int tt = 0; tt < RPB / TROWS; ++tt) {
        const int grow = rowbase + tt * TROWS + g;
        const float* xa = input + ((size_t)b * HW + grow) * EDIM;

        // ---- phase A ----
        float p[NS];
#pragma unroll
        for (int s = 0; s < NS; ++s) p[s] = 0.f;
        float s1 = 0.f, s2 = 0.f;
#pragma unroll
        for (int c = 0; c < 4; ++c) {
            const int off = (c * 16 + j) * 4;
            const float4 x = *reinterpret_cast<const float4*>(xa + off);
            *reinterpret_cast<float4*>(&stage[g][off]) = x;
            s1 += x.x + x.y + x.z + x.w;
            s2 += x.x * x.x + x.y * x.y + x.z * x.z + x.w * x.w;
#pragma unroll
            for (int s = 0; s < NS; ++s) {
                const float4 gg = *reinterpret_cast<const float4*>(&G[s][off]);
                p[s] += x.x * gg.x + x.y * gg.y + x.z * gg.z + x.w * gg.w;
            }
        }
#pragma unroll
        for (int m = 1; m < 16; m <<= 1) {
            s1 += __shfl_xor(s1, m); s2 += __shfl_xor(s2, m);
#pragma unroll
            for (int s = 0; s < NS; ++s) p[s] += __shfl_xor(p[s], m);
        }
        const float mean = s1 * (1.0f / EDIM);
        const float rstd = rsqrtf(s2 * (1.0f / EDIM) - mean * mean + EPS_LN);
        float mx = -1e30f;
#pragma unroll
        for (int s = 0; s < NS; ++s) {
            p[s] = rstd * (p[s] - mean * gqbq_s[0][s]) + gqbq_s[1][s];
            mx = fmaxf(mx, p[s]);
        }
        float tot = 0.f;
#pragma unroll
        for (int s = 0; s < NS; ++s) { p[s] = __expf(p[s] - mx); tot += p[s]; }
        const float inv = 1.0f / tot;
#pragma unroll
        for (int s = 0; s < NS; ++s) p[s] *= inv;

        if (j == 0) {
#pragma unroll
            for (int sq = 0; sq < 4; ++sq)
                *reinterpret_cast<float4*>(&wrec[g][sq * 4]) =
                    make_float4(p[sq * 4], p[sq * 4 + 1], p[sq * 4 + 2], p[sq * 4 + 3]);
            wrec[g][16] = rstd;
            wrec[g][17] = rstd * mean;
            if (LAST) {
#pragma unroll
                for (int s = 0; s < NS; ++s)
                    attn_out[((size_t)(b * NS + s)) * HW + grow] = p[s];
            }
        }
        __syncthreads();

        // ---- phase B: wave w accumulates slots 4w..4w+3 from staged x ----
        {
            const int ch = lane * 4;
            const int sbase = w * 4;
#pragma unroll
            for (int r = 0; r < TROWS; ++r) {
                const float4 xv = *reinterpret_cast<const float4*>(&stage[r][ch]);
                const float4 at = *reinterpret_cast<const float4*>(&wrec[r][sbase]);
                const float rr = wrec[r][16];
                const float rm = wrec[r][17];
                float wg;
                wg = at.x * rr;
                acc[0][0] += wg * xv.x; acc[0][1] += wg * xv.y;
                acc[0][2] += wg * xv.z; acc[0][3] += wg * xv.w;
                S[0] += at.x; A[0] += at.x * rm;
                wg = at.y * rr;
                acc[1][0] += wg * xv.x; acc[1][1] += wg * xv.y;
                acc[1][2] += wg * xv.z; acc[1][3] += wg * xv.w;
                S[1] += at.y; A[1] += at.y * rm;
                wg = at.z * rr;
                acc[2][0] += wg * xv.x; acc[2][1] += wg * xv.y;
                acc[2][2] += wg * xv.z; acc[2][3] += wg * xv.w;
                S[2] += at.z; A[2] += at.z * rm;
                wg = at.w * rr;
                acc[3][0] += wg * xv.x; acc[3][1] += wg * xv.y;
                acc[3][2] += wg * xv.z; acc[3][3] += wg * xv.w;
                S[3] += at.w; A[3] += at.w * rm;
            }
        }
        __syncthreads();
    }

    // epilogue: each wave writes its own 4 slots
#pragma unroll
    for (int si = 0; si < 4; ++si) {
        *reinterpret_cast<float4*>(
            pacc + ((size_t)blockIdx.x * NS + w * 4 + si) * EDIM + lane * 4) =
            make_float4(acc[si][0], acc[si][1], acc[si][2], acc[si][3]);
    }
    if (lane == 0) {
#pragma unroll
        for (int si = 0; si < 4; ++si) {
            psum[blockIdx.x * 32 + w * 4 + si] = S[si];
            psum[blockIdx.x * 32 + 16 + w * 4 + si] = A[si];
        }
    }
}

// G1: partial reduce + ub + updates = ub @ w_v.T.  grid 256: (rt 0..127) x (ct 0..1)
__global__ __launch_bounds__(256) void k_upd(
    const float* __restrict__ pacc, const float* __restrict__ psum,
    const float* __restrict__ g_kv, const float* __restrict__ b_kv,
    const float* __restrict__ w_vT, float* __restrict__ updates) {
    const int rt = blockIdx.x >> 1;
    const int ct = blockIdx.x & 1;
    const int row0 = rt * 4;
    const int b = row0 >> 4;
    const int s0 = row0 & 15;
    const int t = threadIdx.x;
    __shared__ __align__(16) float ub[4][EDIM];
    __shared__ float sSA[4][2];

    if (t < 8) {
        const int r = t & 3;
        const int isA = t >> 2;
        float v = 0.f;
        for (int p = 0; p < BPB; ++p)
            v += psum[(b * BPB + p) * 32 + isA * 16 + s0 + r];
        sSA[r][isA] = v;
    }
    __syncthreads();
#pragma unroll
    for (int r = 0; r < 4; ++r) {
        float V = 0.f;
        for (int p = 0; p < BPB; ++p)
            V += pacc[((size_t)(b * BPB + p) * NS + s0 + r) * EDIM + t];
        const float Sv = sSA[r][0], Av = sSA[r][1];
        ub[r][t] = (g_kv[t] * (V - Av) + b_kv[t] * Sv) / (Sv + EPS_ATTN);
    }
    __syncthreads();

    const int c = ct * 128 + (t & 127);
    const int half = t >> 7;       // 2 rows per thread
    const float* u0 = ub[2 * half];
    const float* u1 = ub[2 * half + 1];
    float a0 = 0.f, a1 = 0.f;
#pragma unroll 4
    for (int j = 0; j < EDIM; j += 4) {
        const float4 x0 = *reinterpret_cast<const float4*>(u0 + j);
        const float4 x1 = *reinterpret_cast<const float4*>(u1 + j);
        const float w0 = w_vT[(size_t)j * EDIM + c];
        const float w1 = w_vT[(size_t)(j + 1) * EDIM + c];
        const float w2 = w_vT[(size_t)(j + 2) * EDIM + c];
        const float w3 = w_vT[(size_t)(j + 3) * EDIM + c];
        a0 += x0.x * w0 + x0.y * w1 + x0.z * w2 + x0.w * w3;
        a1 += x1.x * w0 + x1.y * w1 + x1.z * w2 + x1.w * w3;
    }
    updates[(size_t)(row0 + 2 * half) * EDIM + c] = a0;
    updates[(size_t)(row0 + 2 * half + 1) * EDIM + c] = a1;
}

// G2a: gi = upd @ w_ih.T + b_ih (ct 0..2), gh = qprev @ w_hh.T + b_hh (ct 3..5).
// grid 768: rt = bid/6 (4 rows), ct = bid%6 (256 cols).
__global__ __launch_bounds__(256) void k_gates(
    const float* __restrict__ updates, const float* __restrict__ qprev,
    const float* __restrict__ w_ihT, const float* __restrict__ w_hhT,
    const float* __restrict__ b_ih, const float* __restrict__ b_hh,
    float* __restrict__ gig) {
    const int rt = blockIdx.x / 6;
    const int ct = blockIdx.x % 6;
    const int row0 = rt * 4;
    const int t = threadIdx.x;
    const bool ih = ct < 3;
    const int lc = (ih ? ct : ct - 3) * 256 + t;   // 0..767
    const float* __restrict__ src = ih ? updates : qprev;
    const float* __restrict__ wT = ih ? w_ihT : w_hhT;

    __shared__ __align__(16) float in4[4][EDIM];
#pragma unroll
    for (int r = 0; r < 4; ++r)
        in4[r][t] = src[(size_t)(row0 + r) * EDIM + t];
    __syncthreads();

    float a0 = 0.f, a1 = 0.f, a2 = 0.f, a3 = 0.f;
#pragma unroll 4
    for (int j = 0; j < EDIM; j += 4) {
        const float4 x0 = *reinterpret_cast<const float4*>(&in4[0][j]);
        const float4 x1 = *reinterpret_cast<const float4*>(&in4[1][j]);
        const float4 x2 = *reinterpret_cast<const float4*>(&in4[2][j]);
        const float4 x3 = *reinterpret_cast<const float4*>(&in4[3][j]);
        const float w0 = wT[(size_t)j * 768 + lc];
        const float w1 = wT[(size_t)(j + 1) * 768 + lc];
        const float w2 = wT[(size_t)(j + 2) * 768 + lc];
        const float w3 = wT[(size_t)(j + 3) * 768 + lc];
        a0 += x0.x * w0 + x0.y * w1 + x0.z * w2 + x0.w * w3;
        a1 += x1.x * w0 + x1.y * w1 + x1.z * w2 + x1.w * w3;
        a2 += x2.x * w0 + x2.y * w1 + x2.z * w2 + x2.w * w3;
        a3 += x3.x * w0 + x3.y * w1 + x3.z * w2 + x3.w * w3;
    }
    const float bias = ih ? b_ih[lc] : b_hh[lc];
    const int gcol = ih ? lc : 768 + lc;
    gig[(size_t)(row0 + 0) * 1536 + gcol] = a0 + bias;
    gig[(size_t)(row0 + 1) * 1536 + gcol] = a1 + bias;
    gig[(size_t)(row0 + 2) * 1536 + gcol] = a2 + bias;
    gig[(size_t)(row0 + 3) * 1536 + gcol] = a3 + bias;
}

// G2b+G3 fused: recompute GRU pointwise + LN for this block's 4 rows, then
// h1 slice = gelu(ln2 @ w_f1T[:, ct*256..+255] + b_f1).
// grid 512: rt = bid>>2 (4 rows), ct = bid&3 (256 cols).
__global__ __launch_bounds__(256) void k_gruffn1(
    const float* __restrict__ gig, const float* __restrict__ qprev,
    const float* __restrict__ g_2, const float* __restrict__ b_2,
    const float* __restrict__ w_f1T, const float* __restrict__ b_f1,
    float* __restrict__ slots, float* __restrict__ h1) {
    const int rt = blockIdx.x >> 2;
    const int ct = blockIdx.x & 3;
    const int row0 = rt * 4;
    const int t = threadIdx.x;
    const int wave = t >> 6, lane = t & 63;
    __shared__ __align__(16) float ln2[4][EDIM];
    __shared__ float red[4][8];

    float sl[4];
#pragma unroll
    for (int r = 0; r < 4; ++r) {
        const size_t base = (size_t)(row0 + r) * 1536;
        const float ir = gig[base + t];
        const float iz = gig[base + 256 + t];
        const float inn = gig[base + 512 + t];
        const float hr = gig[base + 768 + t];
        const float hz = gig[base + 1024 + t];
        const float hn = gig[base + 1280 + t];
        const float h = qprev[(size_t)(row0 + r) * EDIM + t];
        const float rg = sigmoidf_(ir + hr);
        const float z = sigmoidf_(iz + hz);
        const float n = tanhf(inn + rg * hn);
        sl[r] = (1.0f - z) * n + z * h;
    }
    if (ct == 0) {
#pragma unroll
        for (int r = 0; r < 4; ++r)
            slots[(size_t)(row0 + r) * EDIM + t] = sl[r];
    }
    {
        float a[4], qq[4];
#pragma unroll
        for (int r = 0; r < 4; ++r) { a[r] = sl[r]; qq[r] = sl[r] * sl[r]; }
#pragma unroll
        for (int m = 1; m < 64; m <<= 1) {
#pragma unroll
            for (int r = 0; r < 4; ++r) {
                a[r] += __shfl_xor(a[r], m);
                qq[r] += __shfl_xor(qq[r], m);
            }
        }
        if (lane == 0) {
#pragma unroll
            for (int r = 0; r < 4; ++r) { red[wave][r] = a[r]; red[wave][4 + r] = qq[r]; }
        }
    }
    __syncthreads();
    {
        const float g = g_2[t], bb = b_2[t];
#pragma unroll
        for (int r = 0; r < 4; ++r) {
            const float Sv = red[0][r] + red[1][r] + red[2][r] + red[3][r];
            const float Qv = red[0][4 + r] + red[1][4 + r] + red[2][4 + r] + red[3][4 + r];
            const float mn = Sv * (1.0f / EDIM);
            const float rs = rsqrtf(Qv * (1.0f / EDIM) - mn * mn + EPS_LN);
            ln2[r][t] = (sl[r] - mn) * rs * g + bb;
        }
    }
    __syncthreads();

    const int c = ct * 256 + t;
    float a0 = 0.f, a1 = 0.f, a2 = 0.f, a3 = 0.f;
#pragma unroll 4
    for (int j = 0; j < EDIM; j += 4) {
        const float4 x0 = *reinterpret_cast<const float4*>(&ln2[0][j]);
        const float4 x1 = *reinterpret_cast<const float4*>(&ln2[1][j]);
        const float4 x2 = *reinterpret_cast<const float4*>(&ln2[2][j]);
        const float4 x3 = *reinterpret_cast<const float4*>(&ln2[3][j]);
        const float w0 = w_f1T[(size_t)j * FFND + c];
        const float w1 = w_f1T[(size_t)(j + 1) * FFND + c];
        const float w2 = w_f1T[(size_t)(j + 2) * FFND + c];
        const float w3 = w_f1T[(size_t)(j + 3) * FFND + c];
        a0 += x0.x * w0 + x0.y * w1 + x0.z * w2 + x0.w * w3;
        a1 += x1.x * w0 + x1.y * w1 + x1.z * w2 + x1.w * w3;
        a2 += x2.x * w0 + x2.y * w1 + x2.z * w2 + x2.w * w3;
        a3 += x3.x * w0 + x3.y * w1 + x3.z * w2 + x3.w * w3;
    }
    const float bf = b_f1[c];
    h1[(size_t)(row0 + 0) * FFND + c] = gelu_(a0 + bf);
    h1[(size_t)(row0 + 1) * FFND + c] = gelu_(a1 + bf);
    h1[(size_t)(row0 + 2) * FFND + c] = gelu_(a2 + bf);
    h1[(size_t)(row0 + 3) * FFND + c] = gelu_(a3 + bf);
}

// G4+G5 fused: q = slots + h1 @ w_f2.T + b_f2 (+adjust), then (if do_qpk)
// LN(q) @ W and gq/bq scalars.  grid 256 blocks x 2 rows.
__global__ __launch_bounds__(256) void k_ffn2qpk(
    const float* __restrict__ h1, const float* __restrict__ slots,
    const float* __restrict__ w_f2T, const float* __restrict__ b_f2,
    const float* __restrict__ query,
    const float* __restrict__ g_q, const float* __restrict__ b_q,
    const float* __restrict__ W,
    const float* __restrict__ g_kv, const float* __restrict__ b_kv,
    float* __restrict__ q_out, float* __restrict__ qpk, float* __restrict__ gqbq,
    int adjust, int do_qpk) {
    const int row0 = blockIdx.x * 2;
    const int t = threadIdx.x;
    const int wave = t >> 6, lane = t & 63;
    __shared__ __align__(16) float in2[2][FFND];
    __shared__ float red[4][4];
    __shared__ __align__(16) float qn[2][EDIM];

#pragma unroll
    for (int r = 0; r < 2; ++r)
        *reinterpret_cast<float4*>(&in2[r][t * 4]) =
            *reinterpret_cast<const float4*>(h1 + (size_t)(row0 + r) * FFND + t * 4);
    __syncthreads();
    float a0 = 0.f, a1 = 0.f;
#pragma unroll 4
    for (int j = 0; j < FFND; j += 4) {
        const float4 x0 = *reinterpret_cast<const float4*>(&in2[0][j]);
        const float4 x1 = *reinterpret_cast<const float4*>(&in2[1][j]);
        const float w0 = w_f2T[(size_t)j * EDIM + t];
        const float w1 = w_f2T[(size_t)(j + 1) * EDIM + t];
        const float w2 = w_f2T[(size_t)(j + 2) * EDIM + t];
        const float w3 = w_f2T[(size_t)(j + 3) * EDIM + t];
        a0 += x0.x * w0 + x0.y * w1 + x0.z * w2 + x0.w * w3;
        a1 += x1.x * w0 + x1.y * w1 + x1.z * w2 + x1.w * w3;
    }
    const float bf = b_f2[t];
    float v0 = slots[(size_t)row0 * EDIM + t] + a0 + bf;
    float v1 = slots[(size_t)(row0 + 1) * EDIM + t] + a1 + bf;
    if (adjust) {
        const float qq0 = query[(size_t)row0 * EDIM + t];
        const float qq1 = query[(size_t)(row0 + 1) * EDIM + t];
        v0 = (v0 + qq0) - qq0;
        v1 = (v1 + qq1) - qq1;
    }
    q_out[(size_t)row0 * EDIM + t] = v0;
    q_out[(size_t)(row0 + 1) * EDIM + t] = v1;

    if (!do_qpk) return;

    {
        float a0r = v0, q0 = v0 * v0, a1r = v1, q1 = v1 * v1;
#pragma unroll
        for (int m = 1; m < 64; m <<= 1) {
            a0r += __shfl_xor(a0r, m); q0 += __shfl_xor(q0, m);
            a1r += __shfl_xor(a1r, m); q1 += __shfl_xor(q1, m);
        }
        if (lane == 0) { red[wave][0] = a0r; red[wave][1] = q0; red[wave][2] = a1r; red[wave][3] = q1; }
    }
    __syncthreads();
    {
        const float S0 = red[0][0] + red[1][0] + red[2][0] + red[3][0];
        const float Q0 = red[0][1] + red[1][1] + red[2][1] + red[3][1];
        const float S1 = red[0][2] + red[1][2] + red[2][2] + red[3][2];
        const float Q1 = red[0][3] + red[1][3] + red[2][3] + red[3][3];
        const float m0 = S0 * (1.0f / EDIM);
        const float r0 = rsqrtf(Q0 * (1.0f / EDIM) - m0 * m0 + EPS_LN);
        const float m1 = S1 * (1.0f / EDIM);
        const float r1 = rsqrtf(Q1 * (1.0f / EDIM) - m1 * m1 + EPS_LN);
        const float g = g_q[t], bb = b_q[t];
        qn[0][t] = (v0 - m0) * r0 * g + bb;
        qn[1][t] = (v1 - m1) * r1 * g + bb;
    }
    __syncthreads();
    float p0 = 0.f, p1 = 0.f;
#pragma unroll 4
    for (int j = 0; j < EDIM; j += 4) {
        const float4 x0 = *reinterpret_cast<const float4*>(&qn[0][j]);
        const float4 x1 = *reinterpret_cast<const float4*>(&qn[1][j]);
        const float w0 = W[(size_t)j * EDIM + t];
        const float w1 = W[(size_t)(j + 1) * EDIM + t];
        const float w2 = W[(size_t)(j + 2) * EDIM + t];
        const float w3 = W[(size_t)(j + 3) * EDIM + t];
        p0 += x0.x * w0 + x0.y * w1 + x0.z * w2 + x0.w * w3;
        p1 += x1.x * w0 + x1.y * w1 + x1.z * w2 + x1.w * w3;
    }
    qpk[(size_t)row0 * EDIM + t] = p0;
    qpk[(size_t)(row0 + 1) * EDIM + t] = p1;
    {
        const float gk = g_kv[t], bk = b_kv[t];
        float u0 = p0 * gk, w0 = p0 * bk, u1 = p1 * gk, w1 = p1 * bk;
#pragma unroll
        for (int m = 1; m < 64; m <<= 1) {
            u0 += __shfl_xor(u0, m); w0 += __shfl_xor(w0, m);
            u1 += __shfl_xor(u1, m); w1 += __shfl_xor(w1, m);
        }
        __syncthreads();
        if (lane == 0) { red[wave][0] = u0; red[wave][1] = w0; red[wave][2] = u1; red[wave][3] = w1; }
        __syncthreads();
        if (t == 0) {
            const int b = row0 >> 4;
            const int sl = row0 & 15;
            gqbq[b * 32 + sl] = red[0][0] + red[1][0] + red[2][0] + red[3][0];
            gqbq[b * 32 + 16 + sl] = red[0][1] + red[1][1] + red[2][1] + red[3][1];
            gqbq[b * 32 + sl + 1] = red[0][2] + red[1][2] + red[2][2] + red[3][2];
            gqbq[b * 32 + 16 + sl + 1] = red[0][3] + red[1][3] + red[2][3] + red[3][3];
        }
    }
}

extern "C" void kernel_launch(void* const* d_in, const int* in_sizes, int n_in,
                              void* d_out, int out_size, void* d_ws, size_t ws_size,
                              hipStream_t stream) {
    const float* input = (const float*)d_in[0];
    const float* query = (const float*)d_in[1];
    const float* g_kv = (const float*)d_in[2];
    const float* b_kv = (const float*)d_in[3];
    const float* w_k = (const float*)d_in[4];
    const float* w_v = (const float*)d_in[5];
    const float* g_q = (const float*)d_in[6];
    const float* b_q = (const float*)d_in[7];
    const float* w_q = (const float*)d_in[8];
    const float* w_ih = (const float*)d_in[9];
    const float* w_hh = (const float*)d_in[10];
    const float* b_ih = (const float*)d_in[11];
    const float* b_hh = (const float*)d_in[12];
    const float* g_2 = (const float*)d_in[13];
    const float* b_2 = (const float*)d_in[14];
    const float* w_f1 = (const float*)d_in[15];
    const float* b_f1 = (const float*)d_in[16];
    const float* w_f2 = (const float*)d_in[17];
    const float* b_f2 = (const float*)d_in[18];

    float* ws = (float*)d_ws;
    float* W = ws;        ws += 65536;
    float* qpk = ws;      ws += 131072;
    float* gqbq = ws;     ws += 1024;
    float* psum = ws;     ws += 32768;
    float* q_ws = ws;     ws += 131072;
    float* updates = ws;  ws += 131072;
    float* slots = ws;    ws += 131072;
    float* w_vT = ws;     ws += 65536;
    float* w_ihT = ws;    ws += 196608;
    float* w_hhT = ws;    ws += 196608;
    float* w_f1T = ws;    ws += 262144;
    float* w_f2T = ws;    ws += 262144;
    float* pacc = ws;     ws += (size_t)NB * BPB * NS * EDIM;   // 16 MB
    float* gig = pacc;                        // 512*1536 overlay (after k_upd)
    float* h1 = pacc + 786432;                // 512*1024 overlay

    float* out_q = (float*)d_out;
    float* out_attn = out_q + (size_t)NB * NS * EDIM;

    k_prep<<<256, 256, 0, stream>>>(w_q, w_k, W);
    k_tr<<<16, 256, 0, stream>>>(w_v, w_vT, 256, 256);
    k_tr<<<48, 256, 0, stream>>>(w_ih, w_ihT, 768, 256);
    k_tr<<<48, 256, 0, stream>>>(w_hh, w_hhT, 768, 256);
    k_tr<<<64, 256, 0, stream>>>(w_f1, w_f1T, 1024, 256);
    k_tr<<<64, 256, 0, stream>>>(w_f2, w_f2T, 256, 1024);
    k_qproj<<<512, 256, 0, stream>>>(query, g_q, b_q, W, g_kv, b_kv, qpk, gqbq);

    const float* qprev[3] = {query, q_ws, q_ws};
    float* qdst[3] = {q_ws, q_ws, out_q};
    const int adj[3] = {0, 1, 0};

    for (int it = 0; it < 3; ++it) {
        const bool last = (it == 2);
        if (last)
            k_bigpass<true><<<NB * BPB, 256, 0, stream>>>(input, qpk, gqbq, g_kv, pacc, psum, out_attn);
        else
            k_bigpass<false><<<NB * BPB, 256, 0, stream>>>(input, qpk, gqbq, g_kv, pacc, psum, nullptr);
        k_upd<<<256, 256, 0, stream>>>(pacc, psum, g_kv, b_kv, w_vT, updates);
        k_gates<<<768, 256, 0, stream>>>(updates, qprev[it], w_ihT, w_hhT, b_ih, b_hh, gig);
        k_gruffn1<<<512, 256, 0, stream>>>(gig, qprev[it], g_2, b_2, w_f1T, b_f1, slots, h1);
        k_ffn2qpk<<<256, 256, 0, stream>>>(h1, slots, w_f2T, b_f2, query, g_q, b_q, W,
                                           g_kv, b_kv, qdst[it], qpk, gqbq,
                                           adj[it], last ? 0 : 1);
    }
}